// Round 2
// baseline (759.079 us; speedup 1.0000x reference)
//
#include <hip/hip_runtime.h>

// Problem constants (GCN_61065845014917)
#define B_   4
#define C_   1024
#define D_   768
#define H_   12
#define E_   32
#define K_   2
#define S_   24
#define V_   8
#define P_   512
#define NT_  256
#define EMB_ 768
#define BLK_ 64
#define NL_  97
#define DNT_ 1024     // D+NT
#define KHT_ 1792     // 2D+NT
#define KBIL_ 49152   // EMB*BLK
#define NPAD_ 128     // NL padded for MFMA

typedef __bf16 bf16x8 __attribute__((ext_vector_type(8)));
typedef float  f32x4  __attribute__((ext_vector_type(4)));

__device__ __forceinline__ float b2f(unsigned short u) {
    return (float)__builtin_bit_cast(__bf16, u);
}
__device__ __forceinline__ unsigned short f2b(float f) {
    return __builtin_bit_cast(unsigned short, (__bf16)f);   // RNE
}
// dtype-dispatched input load / output store (isf=1: f32 buffers, isf=0: bf16)
__device__ __forceinline__ float ld_in(const void* p, size_t i, int isf) {
    return isf ? ((const float*)p)[i] : b2f(((const unsigned short*)p)[i]);
}
__device__ __forceinline__ void st_out(void* p, size_t i, float v, int isf) {
    if (isf) ((float*)p)[i] = v;
    else     ((unsigned short*)p)[i] = f2b(v);
}
// per-wave inline dtype probe: 64 even-index ushorts of sequence_output.
__device__ __forceinline__ int probe_isf(const void* seq) {
    unsigned short u = ((const unsigned short*)seq)[2 * (threadIdx.x & 63)];
    int huge = !(fabsf(b2f(u)) <= 1e10f);          // catches NaN
    unsigned long long zb = __ballot(u == 0);
    return __any(huge) || (__popcll(zb) > 56);
}

// ---------------------------------------------------------------------------
// K1 fused prep: [0,256) gather, [256,1792) eatt, [1792,2560) t_seq,
//                [2560,3232) t_w, [3232,4000) t_bil(64k/blk)
#define PREP_GATHER 256
#define PREP_EATT   (PREP_GATHER + B_*E_*H_)     // +1536 -> 1792
#define PREP_TSEQ   (PREP_EATT + 768)            // -> 2560
#define PREP_TW     (PREP_TSEQ + 672)            // -> 3232
#define PREP_TBIL   (PREP_TW + 768)              // -> 4000

__global__ __launch_bounds__(256) void k_prep(
    const void* __restrict__ seq, const void* __restrict__ att,
    const int* __restrict__ epos, const int* __restrict__ spos,
    const int* __restrict__ vpos, const void* __restrict__ ntype,
    const void* __restrict__ Wh, const void* __restrict__ Wt_,
    const void* __restrict__ Wb,
    float* __restrict__ enth, unsigned short* __restrict__ e_att,
    unsigned short* __restrict__ seqT,
    unsigned short* __restrict__ WtH, unsigned short* __restrict__ WtT,
    unsigned short* __restrict__ WtB,
    void* __restrict__ outv, long long moff, long long soff, long long voff)
{
    __shared__ __align__(16) unsigned char smem[12544];
    int blk = blockIdx.x, tid = threadIdx.x;
    int isf = probe_isf(seq);
    if (blk < PREP_GATHER) {
        if (blk < B_ * E_) {
            int b = blk / E_, e = blk % E_;
            int i0 = epos[(b * E_ + e) * K_ + 0] + 1;
            int i1 = epos[(b * E_ + e) * K_ + 1] + 1;
            size_t r0 = ((size_t)b * C_ + i0) * D_;
            size_t r1 = ((size_t)b * C_ + i1) * D_;
            size_t m0 = (size_t)moff + ((size_t)(b * E_ * K_) + 2 * e) * D_;
            size_t m1 = m0 + D_;
            float* eh = enth + (size_t)(b * E_ + e) * DNT_;
            for (int d = tid; d < D_; d += 256) {
                float a = ld_in(seq, r0 + d, isf);
                float c = ld_in(seq, r1 + d, isf);
                st_out(outv, m0 + d, a, isf);
                st_out(outv, m1 + d, c, isf);
                float mx = fmaxf(a, c);
                eh[d] = mx + logf(expf(a - mx) + expf(c - mx));
            }
            size_t nt0 = (size_t)(b * E_ + e) * NT_;
            for (int j = tid; j < NT_; j += 256) eh[D_ + j] = ld_in(ntype, nt0 + j, isf);
        } else if (blk < B_ * E_ + B_ * S_) {
            int t = blk - B_ * E_; int b = t / S_, s = t % S_;
            int i = spos[b * S_ + s] + 1;
            size_t r = ((size_t)b * C_ + i) * D_;
            size_t o = (size_t)soff + (size_t)(b * S_ + s) * D_;
            for (int d = tid; d < D_; d += 256) st_out(outv, o + d, ld_in(seq, r + d, isf), isf);
        } else {
            int t = blk - B_ * E_ - B_ * S_; int b = t / V_, v = t % V_;
            int i = vpos[b * V_ + v] + 1;
            size_t r = ((size_t)b * C_ + i) * D_;
            size_t o = (size_t)voff + (size_t)(b * V_ + v) * D_;
            for (int d = tid; d < D_; d += 256) st_out(outv, o + d, ld_in(seq, r + d, isf), isf);
        }
    } else if (blk < PREP_EATT) {
        int t = blk - PREP_GATHER;
        int b = t / (E_ * H_); int r = t % (E_ * H_); int e = r / H_; int h = r % H_;
        int i0 = epos[(b * E_ + e) * K_ + 0] + 1;
        int i1 = epos[(b * E_ + e) * K_ + 1] + 1;
        size_t a0 = (((size_t)b * H_ + h) * C_ + i0) * C_;
        size_t a1 = (((size_t)b * H_ + h) * C_ + i1) * C_;
        unsigned short* o = e_att + (((size_t)(b * E_ + e)) * H_ + h) * C_;
        for (int c = tid; c < C_; c += 256)
            o[c] = f2b(0.5f * (ld_in(att, a0 + c, isf) + ld_in(att, a1 + c, isf)));
    } else if (blk < PREP_TSEQ) {
        int t = blk - PREP_EATT;                 // b*192 + ct*12 + dt
        int b = t / 192; int r = t % 192; int ct = r / 12; int dt = r % 12;
        typedef unsigned short row65[65];
        row65* tile = (row65*)smem;
        for (int idx = tid; idx < 4096; idx += 256) {
            int cc = idx >> 6, dd = idx & 63;
            tile[cc][dd] = f2b(ld_in(seq, ((size_t)b * C_ + ct * 64 + cc) * D_ + dt * 64 + dd, isf));
        }
        __syncthreads();
        for (int idx = tid; idx < 4096; idx += 256) {
            int dd = idx >> 6, cc = idx & 63;
            seqT[((size_t)b * D_ + dt * 64 + dd) * C_ + ct * 64 + cc] = tile[cc][dd];
        }
    } else if (blk < PREP_TW) {
        int t = blk - PREP_TSEQ;                 // mat*336 + kt*12 + nt
        int mat = t / 336; int r = t % 336; int kt = r / 12; int nt = r % 12;
        const void* in = mat ? Wt_ : Wh;
        unsigned short* out = mat ? WtT : WtH;
        typedef unsigned short row65[65];
        row65* tile = (row65*)smem;
        for (int idx = tid; idx < 4096; idx += 256) {
            int kk = idx >> 6, nn = idx & 63;
            tile[kk][nn] = f2b(ld_in(in, ((size_t)kt * 64 + kk) * EMB_ + nt * 64 + nn, isf));
        }
        __syncthreads();
        for (int idx = tid; idx < 4096; idx += 256) {
            int nn = idx >> 6, kk = idx & 63;
            out[((size_t)nt * 64 + nn) * KHT_ + kt * 64 + kk] = tile[kk][nn];
        }
    } else {
        int t = blk - PREP_TW;                   // 64 k-cols per block
        int k0 = t << 6;
        unsigned short* raw = (unsigned short*)smem;   // [64*97]
        for (int idx = tid; idx < 64 * NL_; idx += 256)
            raw[idx] = f2b(ld_in(Wb, (size_t)k0 * NL_ + idx, isf));
        __syncthreads();
        int kk = tid & 63, nq = tid >> 6;              // 4 quarters x 32 n
        for (int i = 0; i < 32; i++) {
            int n = nq * 32 + i;
            unsigned short v = (n < NL_) ? raw[kk * NL_ + n] : (unsigned short)0;
            WtB[(size_t)n * KBIL_ + k0 + kk] = v;
        }
    }
}

// ---------------------------------------------------------------------------
// K2 fused mid: [0,2048) htatt, [2048,4096) xbuild, [4096,4352) zero logitsF
__global__ __launch_bounds__(256) void k_mid(
    const unsigned short* __restrict__ e_att, const float* __restrict__ enth,
    const int* __restrict__ hts,
    unsigned short* __restrict__ htb,
    unsigned short* __restrict__ Xh, unsigned short* __restrict__ Xt,
    float* __restrict__ logitsF)
{
    __shared__ float red[4];
    int blk = blockIdx.x, tid = threadIdx.x;
    if (blk < B_ * P_) {
        int b = blk >> 9;
        int he = hts[blk * 2 + 0], te = hts[blk * 2 + 1];
        const unsigned short* ph = e_att + (size_t)(b * E_ + he) * H_ * C_;
        const unsigned short* pt = e_att + (size_t)(b * E_ + te) * H_ * C_;
        float v[4]; float ls = 0.f;
        for (int ci = 0; ci < 4; ci++) {
            int c = tid + (ci << 8);
            float acc = 0.f;
#pragma unroll
            for (int h = 0; h < H_; h++) acc += b2f(ph[h * C_ + c]) * b2f(pt[h * C_ + c]);
            acc *= (1.0f / (float)H_);
            v[ci] = acc; ls += acc;
        }
        for (int off = 32; off > 0; off >>= 1) ls += __shfl_down(ls, off, 64);
        if ((tid & 63) == 0) red[tid >> 6] = ls;
        __syncthreads();
        float inv = 1.0f / (red[0] + red[1] + red[2] + red[3] + 1e-5f);
        for (int ci = 0; ci < 4; ci++)
            htb[((size_t)blk << 10) + tid + (ci << 8)] = f2b(v[ci] * inv);
    } else if (blk < 2 * B_ * P_) {
        int m = blk - B_ * P_; int b = m >> 9;
        int eh = hts[m * 2 + 0], et = hts[m * 2 + 1];
        const float* sh = enth + (size_t)(b * E_ + eh) * DNT_;
        const float* st = enth + (size_t)(b * E_ + et) * DNT_;
        for (int k = tid; k < DNT_; k += 256) {
            Xh[(size_t)m * KHT_ + k] = f2b(sh[k]);
            Xt[(size_t)m * KHT_ + k] = f2b(st[k]);
        }
    } else {
        int t = blk - 2 * B_ * P_;               // 256 blocks zero 1 MB
        ((float4*)logitsF)[(size_t)t * 256 + tid] = make_float4(0.f, 0.f, 0.f, 0.f);
    }
}

// ---------------------------------------------------------------------------
// bf16 MFMA GEMM, 64x64 tile, 4 waves 2x2, K-step 32, LDS staging (coalesced),
// register prefetch.
// zmode 0 (rs): z = batch; epilogue writes bf16 into Xh/Xt cols DNT_+n.
// zmode 1 (ht): z = mat (0=head,1=tail); epilogue bf16 tanh(acc+bias) -> oY.
__global__ __launch_bounds__(256) void k_gemm(
    const unsigned short* __restrict__ A0, const unsigned short* __restrict__ A1,
    const unsigned short* __restrict__ B0, const unsigned short* __restrict__ B1,
    long long lda, long long ldb, long long sAz, long long sBz,
    int nsteps, int zmode,
    const void* __restrict__ bias0, const void* __restrict__ bias1,
    unsigned short* __restrict__ oY0, unsigned short* __restrict__ oY1,
    unsigned short* __restrict__ oX1, unsigned short* __restrict__ oX2,
    const void* __restrict__ seq)
{
    int n0 = blockIdx.x * 64, m0 = blockIdx.y * 64, z = blockIdx.z;
    const unsigned short* Ab; const unsigned short* Bb;
    unsigned short* oY = nullptr; const void* bias = nullptr;
    if (zmode == 0) {
        Ab = A0 + (size_t)z * sAz; Bb = B0 + (size_t)z * sBz;
    } else {
        Ab = z ? A1 : A0; Bb = z ? B1 : B0;
        oY = z ? oY1 : oY0; bias = z ? bias1 : bias0;
    }
    __shared__ __align__(16) unsigned short a_lds[64][40];
    __shared__ __align__(16) unsigned short b_lds[64][40];
    int tid = threadIdx.x, lane = tid & 63, w = tid >> 6;
    int wm = (w >> 1) * 32, wn = (w & 1) * 32, q = lane >> 4, l15 = lane & 15;
    f32x4 acc00 = {0.f,0.f,0.f,0.f}, acc01 = acc00, acc10 = acc00, acc11 = acc00;
    int srow = tid >> 2, sch = (tid & 3) * 8;
    const unsigned short* pa = Ab + (size_t)(m0 + srow) * lda + sch;
    const unsigned short* pb = Bb + (size_t)(n0 + srow) * ldb + sch;
    int4 ra = *(const int4*)pa;
    int4 rb = *(const int4*)pb;
    for (int ks = 0; ks < nsteps; ks++) {
        __syncthreads();
        *(int4*)&a_lds[srow][sch] = ra;
        *(int4*)&b_lds[srow][sch] = rb;
        __syncthreads();
        if (ks + 1 < nsteps) {
            ra = *(const int4*)(pa + (size_t)(ks + 1) * 32);
            rb = *(const int4*)(pb + (size_t)(ks + 1) * 32);
        }
        bf16x8 a0 = *(const bf16x8*)&a_lds[wm + l15][q * 8];
        bf16x8 a1 = *(const bf16x8*)&a_lds[wm + 16 + l15][q * 8];
        bf16x8 b0 = *(const bf16x8*)&b_lds[wn + l15][q * 8];
        bf16x8 b1 = *(const bf16x8*)&b_lds[wn + 16 + l15][q * 8];
        acc00 = __builtin_amdgcn_mfma_f32_16x16x32_bf16(a0, b0, acc00, 0, 0, 0);
        acc01 = __builtin_amdgcn_mfma_f32_16x16x32_bf16(a0, b1, acc01, 0, 0, 0);
        acc10 = __builtin_amdgcn_mfma_f32_16x16x32_bf16(a1, b0, acc10, 0, 0, 0);
        acc11 = __builtin_amdgcn_mfma_f32_16x16x32_bf16(a1, b1, acc11, 0, 0, 0);
    }
    f32x4 accs[2][2] = {{acc00, acc01}, {acc10, acc11}};
    int isf = (zmode == 1) ? probe_isf(seq) : 0;
#pragma unroll
    for (int mt = 0; mt < 2; mt++)
#pragma unroll
        for (int nt = 0; nt < 2; nt++) {
            int gmb = m0 + wm + mt * 16 + q * 4;
            int gn  = n0 + wn + nt * 16 + l15;
            if (zmode == 0) {
#pragma unroll
                for (int r = 0; r < 4; r++) {
                    unsigned short v = f2b(accs[mt][nt][r]);
                    size_t o = (size_t)(z * P_ + gmb + r) * KHT_ + DNT_ + gn;
                    oX1[o] = v; oX2[o] = v;
                }
            } else {
                float bv = ld_in(bias, gn, isf);
#pragma unroll
                for (int r = 0; r < 4; r++)
                    oY[(size_t)(gmb + r) * EMB_ + gn] = f2b(tanhf(accs[mt][nt][r] + bv));
            }
        }
}

// ---------------------------------------------------------------------------
// Grouped bilinear v3: pipelined LDS-staged W, counted-vmcnt double buffer.
//   logits[m,n] = sum_i hs[m,i] * ( sum_j ts[m,j] * W[g,i,j,n] )
// Block: 128 m-rows x 128 n-cols x 16 i's (one quarter of one group).
// 8 waves = 2 m-groups x 4 n-groups; each wave: 4 m-subtiles x 2 n-subtiles
// -> each W fragment read from LDS feeds 4 MFMAs (register blocking).
// W slice per i (128n x 64j bf16 = 16 KB) staged via global_load_lds into a
// 2-deep LDS ring; counted s_waitcnt vmcnt(2) keeps the next-next slice in
// flight across raw s_barriers (T3/T4 minimum 2-phase template).
// LDS read swizzle: byte ^= (row&7)<<4, applied on the READ and inverted on
// the GLOBAL SOURCE address (linear LDS dest required by global_load_lds).
__global__ __launch_bounds__(512, 4) void k_bil(
    const unsigned short* __restrict__ hsB, const unsigned short* __restrict__ tsB,
    const unsigned short* __restrict__ WtB, float* __restrict__ logitsF)
{
    // 768 blocks = 8 XCDs x 96; per XCD: 6 (g,ic) combos x 16 m-tiles
    // -> W working set per XCD = 6 x 256 KB = 1.5 MB (L2-fit).
    int bid = blockIdx.x;
    int lin = (bid & 7) * 96 + (bid >> 3);
    int mt  = lin & 15;            // m-tile  [0,16)
    int gic = lin >> 4;            // [0,48)
    int g   = gic >> 2;            // group   [0,12)
    int ic  = gic & 3;             // i-chunk [0,4)
    int m0  = mt * 128;

    int tid = threadIdx.x, lane = tid & 63, w = tid >> 6;
    int q = lane >> 4, l15 = lane & 15;
    int mg = (w >> 2) * 64;        // wave m-base within tile: 0 / 64
    int ng = (w & 3) * 32;         // wave n-base: 0,32,64,96

    __shared__ __align__(16) unsigned short wbuf[2][8192];  // 2 x 16 KB W slices
    __shared__ __align__(16) unsigned short hsT[16][128];   // hs transposed [i][m]

    // ---- stage hsT (tiny) ----
    if (tid < 128) {
        const unsigned short* ph = &hsB[(size_t)(m0 + tid) * EMB_ + g * 64 + ic * 16];
        ushort4 h0 = *(const ushort4*)(ph + 0);
        ushort4 h1 = *(const ushort4*)(ph + 4);
        ushort4 h2 = *(const ushort4*)(ph + 8);
        ushort4 h3 = *(const ushort4*)(ph + 12);
        hsT[ 0][tid] = h0.x; hsT[ 1][tid] = h0.y; hsT[ 2][tid] = h0.z; hsT[ 3][tid] = h0.w;
        hsT[ 4][tid] = h1.x; hsT[ 5][tid] = h1.y; hsT[ 6][tid] = h1.z; hsT[ 7][tid] = h1.w;
        hsT[ 8][tid] = h2.x; hsT[ 9][tid] = h2.y; hsT[10][tid] = h2.z; hsT[11][tid] = h2.w;
        hsT[12][tid] = h3.x; hsT[13][tid] = h3.y; hsT[14][tid] = h3.z; hsT[15][tid] = h3.w;
    }

    // ---- ts A-fragments (invariant over i), direct global loads ----
    bf16x8 a[4][2];
#pragma unroll
    for (int ms = 0; ms < 4; ++ms)
#pragma unroll
        for (int jh = 0; jh < 2; ++jh)
            a[ms][jh] = *(const bf16x8*)&tsB[(size_t)(m0 + mg + ms * 16 + l15) * EMB_
                                             + g * 64 + jh * 32 + q * 8];

    __syncthreads();   // hsT visible; all compiler loads drained before W issues

    // ---- W staging: per thread 2 x 16B per slice; swizzled global source ----
    size_t gbase = (size_t)g * 4096 + (size_t)ic * 16 * 64;   // element base for this block
    int flat0 = tid, flat1 = 512 + tid;
    int n0r = flat0 >> 3, n1r = flat1 >> 3;
    // source j-chunk carries the inverse read-swizzle
    const unsigned short* src0 = WtB + (size_t)n0r * KBIL_ + gbase + ((flat0 & 7) ^ (n0r & 7)) * 8;
    const unsigned short* src1 = WtB + (size_t)n1r * KBIL_ + gbase + ((flat1 & 7) ^ (n1r & 7)) * 8;
    unsigned short* dst0 = &wbuf[0][0] + (size_t)(0 * 512 + w * 64) * 8;   // wave-uniform
    unsigned short* dst1 = &wbuf[0][0] + (size_t)(1 * 512 + w * 64) * 8;

#define STAGE_W(islice, buf)                                                              \
    do {                                                                                  \
        size_t joff = (size_t)(islice) * 64;                                              \
        __builtin_amdgcn_global_load_lds(                                                 \
            (const __attribute__((address_space(1))) void*)(src0 + joff),                 \
            (__attribute__((address_space(3))) void*)(dst0 + (size_t)(buf) * 8192), 16, 0, 0); \
        __builtin_amdgcn_global_load_lds(                                                 \
            (const __attribute__((address_space(1))) void*)(src1 + joff),                 \
            (__attribute__((address_space(3))) void*)(dst1 + (size_t)(buf) * 8192), 16, 0, 0); \
    } while (0)

    STAGE_W(0, 0);
    STAGE_W(1, 1);
    asm volatile("s_waitcnt vmcnt(2)" ::: "memory");   // slice 0 landed; slice 1 in flight
    __builtin_amdgcn_s_barrier();

    f32x4 acc[4][2];
#pragma unroll
    for (int ms = 0; ms < 4; ++ms)
#pragma unroll
        for (int nt = 0; nt < 2; ++nt)
            acc[ms][nt] = (f32x4){0.f, 0.f, 0.f, 0.f};
    const f32x4 zf = {0.f, 0.f, 0.f, 0.f};

    for (int i = 0; i < 16; ++i) {
        int cur = i & 1;
        const char* wb = (const char*)&wbuf[cur][0];
        // swizzled LDS reads: 2 n-subtiles x 2 j-halves
        bf16x8 wf[2][2];
#pragma unroll
        for (int nt = 0; nt < 2; ++nt) {
            int nrow = ng + nt * 16 + l15;
            int sw = (nrow & 7) << 4;
#pragma unroll
            for (int jh = 0; jh < 2; ++jh)
                wf[nt][jh] = *(const bf16x8*)(wb + ((nrow * 128 + jh * 64 + q * 16) ^ sw));
        }
        // P_i = ts x W_i  (8 tiles, 2-chained MFMAs over j-halves)
        f32x4 p[4][2];
#pragma unroll
        for (int ms = 0; ms < 4; ++ms)
#pragma unroll
            for (int nt = 0; nt < 2; ++nt) {
                f32x4 t = __builtin_amdgcn_mfma_f32_16x16x32_bf16(a[ms][0], wf[nt][0], zf, 0, 0, 0);
                p[ms][nt] = __builtin_amdgcn_mfma_f32_16x16x32_bf16(a[ms][1], wf[nt][1], t, 0, 0, 0);
            }
        // fold hs[m, i] (f32) into accumulators
#pragma unroll
        for (int ms = 0; ms < 4; ++ms) {
            ushort4 hv = *(const ushort4*)&hsT[i][mg + ms * 16 + q * 4];
            float h0 = b2f(hv.x), h1 = b2f(hv.y), h2 = b2f(hv.z), h3 = b2f(hv.w);
#pragma unroll
            for (int nt = 0; nt < 2; ++nt) {
                acc[ms][nt][0] += h0 * p[ms][nt][0];
                acc[ms][nt][1] += h1 * p[ms][nt][1];
                acc[ms][nt][2] += h2 * p[ms][nt][2];
                acc[ms][nt][3] += h3 * p[ms][nt][3];
            }
        }
        // pipeline: all waves done reading buf[cur] -> refill it with slice i+2
        asm volatile("" ::: "memory");
        __builtin_amdgcn_s_barrier();
        if (i + 2 < 16) {
            STAGE_W(i + 2, cur);
            asm volatile("s_waitcnt vmcnt(2)" ::: "memory");  // slice i+1 landed
        } else {
            asm volatile("s_waitcnt vmcnt(0)" ::: "memory");  // drain tail
        }
        __builtin_amdgcn_s_barrier();
    }
#undef STAGE_W

#pragma unroll
    for (int ms = 0; ms < 4; ++ms)
#pragma unroll
        for (int nt = 0; nt < 2; ++nt)
#pragma unroll
            for (int r = 0; r < 4; ++r)
                atomicAdd(&logitsF[(size_t)(m0 + mg + ms * 16 + q * 4 + r) * NPAD_
                                   + ng + nt * 16 + l15],
                          acc[ms][nt][r]);
}

// ---------------------------------------------------------------------------
// final: logits out with bias, n<97
__global__ __launch_bounds__(256) void k_fin(
    const float* __restrict__ logitsF, const void* __restrict__ b_bil,
    void* __restrict__ outv, const void* __restrict__ seq)
{
    int isf = probe_isf(seq);
    int idx = blockIdx.x * 256 + threadIdx.x;
    if (idx >= B_ * P_ * NL_) return;
    int m = idx / NL_, n = idx % NL_;
    st_out(outv, idx, logitsF[(size_t)m * NPAD_ + n] + ld_in(b_bil, n, isf), isf);
}

// ---------------------------------------------------------------------------
extern "C" void kernel_launch(void* const* d_in, const int* in_sizes, int n_in,
                              void* d_out, int out_size, void* d_ws, size_t ws_size,
                              hipStream_t stream)
{
    const void* seq    = d_in[0];
    const void* att    = d_in[1];
    const int*  epos   = (const int*)d_in[2];
    const int*  spos   = (const int*)d_in[3];
    const int*  vpos   = (const int*)d_in[4];
    const int*  hts    = (const int*)d_in[5];
    const void* ntype  = d_in[6];
    const void* W_head = d_in[7];
    const void* b_head = d_in[8];
    const void* W_tail = d_in[9];
    const void* b_tail = d_in[10];
    const void* W_bil  = d_in[11];
    const void* b_bil  = d_in[12];

    // output element offsets (dtype-agnostic)
    long long mention_off = (long long)B_ * P_ * NL_;
    long long sent_off    = mention_off + (long long)B_ * E_ * K_ * D_;
    long long virt_off    = sent_off + (long long)B_ * S_ * D_;

    // workspace carve (~50 MB)
    char* p = (char*)d_ws;
    auto alloc = [&](size_t bytes) { void* r = (void*)p; p += (bytes + 255) & ~(size_t)255; return r; };
    unsigned short* e_att   = (unsigned short*)alloc((size_t)B_ * E_ * H_ * C_ * 2);
    unsigned short* htb     = (unsigned short*)alloc((size_t)B_ * P_ * C_ * 2);
    unsigned short* seqT    = (unsigned short*)alloc((size_t)B_ * D_ * C_ * 2);
    unsigned short* WtH     = (unsigned short*)alloc((size_t)EMB_ * KHT_ * 2);
    unsigned short* WtT     = (unsigned short*)alloc((size_t)EMB_ * KHT_ * 2);
    unsigned short* WtB     = (unsigned short*)alloc((size_t)NPAD_ * KBIL_ * 2);
    unsigned short* Xh      = (unsigned short*)alloc((size_t)B_ * P_ * KHT_ * 2);
    unsigned short* Xt      = (unsigned short*)alloc((size_t)B_ * P_ * KHT_ * 2);
    unsigned short* hsB     = (unsigned short*)alloc((size_t)B_ * P_ * EMB_ * 2);
    unsigned short* tsB     = (unsigned short*)alloc((size_t)B_ * P_ * EMB_ * 2);
    float*          logitsF = (float*)alloc((size_t)B_ * P_ * NPAD_ * 4);
    float*          enth    = (float*)alloc((size_t)B_ * E_ * DNT_ * 4);

    dim3 blk(256);
    k_prep<<<PREP_TBIL, blk, 0, stream>>>(
        seq, att, epos, spos, vpos, ntype, W_head, W_tail, W_bil,
        enth, e_att, seqT, WtH, WtT, WtB,
        d_out, mention_off, sent_off, virt_off);
    k_mid<<<2 * B_ * P_ + 256, blk, 0, stream>>>(e_att, enth, hts, htb, Xh, Xt, logitsF);
    // rs GEMM: per batch [512 x 1024] @ [1024 x 768]^T -> X cols 1024..1791
    k_gemm<<<dim3(EMB_ / 64, P_ / 64, B_), blk, 0, stream>>>(
        htb, nullptr, seqT, nullptr, C_, C_,
        (long long)P_ * C_, (long long)D_ * C_, C_ / 32, 0,
        nullptr, nullptr, nullptr, nullptr, Xh, Xt, seq);
    // fused head+tail: [2048 x 1792] @ [1792 x 768]^T, tanh+bias -> bf16 hsB/tsB
    k_gemm<<<dim3(EMB_ / 64, (B_ * P_) / 64, 2), blk, 0, stream>>>(
        Xh, Xt, WtH, WtT, KHT_, KHT_, 0, 0, KHT_ / 32, 1,
        b_head, b_tail, hsB, tsB, nullptr, nullptr, seq);
    // bilinear v3: 768 blocks (16 m-tiles x 12 g x 4 i-chunks), XCD-affine
    k_bil<<<dim3(16 * 12 * 4), dim3(512), 0, stream>>>(hsB, tsB, WtB, logitsF);
    k_fin<<<(B_ * P_ * NL_ + 255) / 256, blk, 0, stream>>>(logitsF, b_bil, d_out, seq);
}

// Round 3
// 412.758 us; speedup vs baseline: 1.8390x; 1.8390x over previous
//
#include <hip/hip_runtime.h>

// Problem constants (GCN_61065845014917)
#define B_   4
#define C_   1024
#define D_   768
#define H_   12
#define E_   32
#define K_   2
#define S_   24
#define V_   8
#define P_   512
#define NT_  256
#define EMB_ 768
#define BLK_ 64
#define NL_  97
#define DNT_ 1024     // D+NT
#define KHT_ 1792     // 2D+NT
#define KBIL_ 49152   // EMB*BLK
#define NPAD_ 128     // NL padded for MFMA

typedef __bf16 bf16x8 __attribute__((ext_vector_type(8)));
typedef float  f32x4  __attribute__((ext_vector_type(4)));

__device__ __forceinline__ float b2f(unsigned short u) {
    return (float)__builtin_bit_cast(__bf16, u);
}
__device__ __forceinline__ unsigned short f2b(float f) {
    return __builtin_bit_cast(unsigned short, (__bf16)f);   // RNE
}
// dtype-dispatched input load / output store (isf=1: f32 buffers, isf=0: bf16)
__device__ __forceinline__ float ld_in(const void* p, size_t i, int isf) {
    return isf ? ((const float*)p)[i] : b2f(((const unsigned short*)p)[i]);
}
__device__ __forceinline__ void st_out(void* p, size_t i, float v, int isf) {
    if (isf) ((float*)p)[i] = v;
    else     ((unsigned short*)p)[i] = f2b(v);
}
// per-wave inline dtype probe: 64 even-index ushorts of sequence_output.
__device__ __forceinline__ int probe_isf(const void* seq) {
    unsigned short u = ((const unsigned short*)seq)[2 * (threadIdx.x & 63)];
    int huge = !(fabsf(b2f(u)) <= 1e10f);          // catches NaN
    unsigned long long zb = __ballot(u == 0);
    return __any(huge) || (__popcll(zb) > 56);
}

// ---------------------------------------------------------------------------
// K1 fused prep: [0,256) gather, [256,1792) eatt, [1792,2560) t_seq,
//                [2560,3232) t_w, [3232,4000) t_bil(64k/blk)
#define PREP_GATHER 256
#define PREP_EATT   (PREP_GATHER + B_*E_*H_)     // +1536 -> 1792
#define PREP_TSEQ   (PREP_EATT + 768)            // -> 2560
#define PREP_TW     (PREP_TSEQ + 672)            // -> 3232
#define PREP_TBIL   (PREP_TW + 768)              // -> 4000

__global__ __launch_bounds__(256) void k_prep(
    const void* __restrict__ seq, const void* __restrict__ att,
    const int* __restrict__ epos, const int* __restrict__ spos,
    const int* __restrict__ vpos, const void* __restrict__ ntype,
    const void* __restrict__ Wh, const void* __restrict__ Wt_,
    const void* __restrict__ Wb,
    float* __restrict__ enth, unsigned short* __restrict__ e_att,
    unsigned short* __restrict__ seqT,
    unsigned short* __restrict__ WtH, unsigned short* __restrict__ WtT,
    unsigned short* __restrict__ WtB,
    void* __restrict__ outv, long long moff, long long soff, long long voff)
{
    __shared__ __align__(16) unsigned char smem[12544];
    int blk = blockIdx.x, tid = threadIdx.x;
    int isf = probe_isf(seq);
    if (blk < PREP_GATHER) {
        if (blk < B_ * E_) {
            int b = blk / E_, e = blk % E_;
            int i0 = epos[(b * E_ + e) * K_ + 0] + 1;
            int i1 = epos[(b * E_ + e) * K_ + 1] + 1;
            size_t r0 = ((size_t)b * C_ + i0) * D_;
            size_t r1 = ((size_t)b * C_ + i1) * D_;
            size_t m0 = (size_t)moff + ((size_t)(b * E_ * K_) + 2 * e) * D_;
            size_t m1 = m0 + D_;
            float* eh = enth + (size_t)(b * E_ + e) * DNT_;
            for (int d = tid; d < D_; d += 256) {
                float a = ld_in(seq, r0 + d, isf);
                float c = ld_in(seq, r1 + d, isf);
                st_out(outv, m0 + d, a, isf);
                st_out(outv, m1 + d, c, isf);
                float mx = fmaxf(a, c);
                eh[d] = mx + logf(expf(a - mx) + expf(c - mx));
            }
            size_t nt0 = (size_t)(b * E_ + e) * NT_;
            for (int j = tid; j < NT_; j += 256) eh[D_ + j] = ld_in(ntype, nt0 + j, isf);
        } else if (blk < B_ * E_ + B_ * S_) {
            int t = blk - B_ * E_; int b = t / S_, s = t % S_;
            int i = spos[b * S_ + s] + 1;
            size_t r = ((size_t)b * C_ + i) * D_;
            size_t o = (size_t)soff + (size_t)(b * S_ + s) * D_;
            for (int d = tid; d < D_; d += 256) st_out(outv, o + d, ld_in(seq, r + d, isf), isf);
        } else {
            int t = blk - B_ * E_ - B_ * S_; int b = t / V_, v = t % V_;
            int i = vpos[b * V_ + v] + 1;
            size_t r = ((size_t)b * C_ + i) * D_;
            size_t o = (size_t)voff + (size_t)(b * V_ + v) * D_;
            for (int d = tid; d < D_; d += 256) st_out(outv, o + d, ld_in(seq, r + d, isf), isf);
        }
    } else if (blk < PREP_EATT) {
        int t = blk - PREP_GATHER;
        int b = t / (E_ * H_); int r = t % (E_ * H_); int e = r / H_; int h = r % H_;
        int i0 = epos[(b * E_ + e) * K_ + 0] + 1;
        int i1 = epos[(b * E_ + e) * K_ + 1] + 1;
        size_t a0 = (((size_t)b * H_ + h) * C_ + i0) * C_;
        size_t a1 = (((size_t)b * H_ + h) * C_ + i1) * C_;
        unsigned short* o = e_att + (((size_t)(b * E_ + e)) * H_ + h) * C_;
        for (int c = tid; c < C_; c += 256)
            o[c] = f2b(0.5f * (ld_in(att, a0 + c, isf) + ld_in(att, a1 + c, isf)));
    } else if (blk < PREP_TSEQ) {
        int t = blk - PREP_EATT;                 // b*192 + ct*12 + dt
        int b = t / 192; int r = t % 192; int ct = r / 12; int dt = r % 12;
        typedef unsigned short row65[65];
        row65* tile = (row65*)smem;
        for (int idx = tid; idx < 4096; idx += 256) {
            int cc = idx >> 6, dd = idx & 63;
            tile[cc][dd] = f2b(ld_in(seq, ((size_t)b * C_ + ct * 64 + cc) * D_ + dt * 64 + dd, isf));
        }
        __syncthreads();
        for (int idx = tid; idx < 4096; idx += 256) {
            int dd = idx >> 6, cc = idx & 63;
            seqT[((size_t)b * D_ + dt * 64 + dd) * C_ + ct * 64 + cc] = tile[cc][dd];
        }
    } else if (blk < PREP_TW) {
        int t = blk - PREP_TSEQ;                 // mat*336 + kt*12 + nt
        int mat = t / 336; int r = t % 336; int kt = r / 12; int nt = r % 12;
        const void* in = mat ? Wt_ : Wh;
        unsigned short* out = mat ? WtT : WtH;
        typedef unsigned short row65[65];
        row65* tile = (row65*)smem;
        for (int idx = tid; idx < 4096; idx += 256) {
            int kk = idx >> 6, nn = idx & 63;
            tile[kk][nn] = f2b(ld_in(in, ((size_t)kt * 64 + kk) * EMB_ + nt * 64 + nn, isf));
        }
        __syncthreads();
        for (int idx = tid; idx < 4096; idx += 256) {
            int nn = idx >> 6, kk = idx & 63;
            out[((size_t)nt * 64 + nn) * KHT_ + kt * 64 + kk] = tile[kk][nn];
        }
    } else {
        int t = blk - PREP_TW;                   // 64 k-cols per block
        int k0 = t << 6;
        unsigned short* raw = (unsigned short*)smem;   // [64*97]
        for (int idx = tid; idx < 64 * NL_; idx += 256)
            raw[idx] = f2b(ld_in(Wb, (size_t)k0 * NL_ + idx, isf));
        __syncthreads();
        int kk = tid & 63, nq = tid >> 6;              // 4 quarters x 32 n
        for (int i = 0; i < 32; i++) {
            int n = nq * 32 + i;
            unsigned short v = (n < NL_) ? raw[kk * NL_ + n] : (unsigned short)0;
            WtB[(size_t)n * KBIL_ + k0 + kk] = v;
        }
    }
}

// ---------------------------------------------------------------------------
// K2 fused mid: [0,2048) htatt, [2048,4096) xbuild, [4096,4352) zero logitsF
__global__ __launch_bounds__(256) void k_mid(
    const unsigned short* __restrict__ e_att, const float* __restrict__ enth,
    const int* __restrict__ hts,
    unsigned short* __restrict__ htb,
    unsigned short* __restrict__ Xh, unsigned short* __restrict__ Xt,
    float* __restrict__ logitsF)
{
    __shared__ float red[4];
    int blk = blockIdx.x, tid = threadIdx.x;
    if (blk < B_ * P_) {
        int b = blk >> 9;
        int he = hts[blk * 2 + 0], te = hts[blk * 2 + 1];
        const unsigned short* ph = e_att + (size_t)(b * E_ + he) * H_ * C_;
        const unsigned short* pt = e_att + (size_t)(b * E_ + te) * H_ * C_;
        float v[4]; float ls = 0.f;
        for (int ci = 0; ci < 4; ci++) {
            int c = tid + (ci << 8);
            float acc = 0.f;
#pragma unroll
            for (int h = 0; h < H_; h++) acc += b2f(ph[h * C_ + c]) * b2f(pt[h * C_ + c]);
            acc *= (1.0f / (float)H_);
            v[ci] = acc; ls += acc;
        }
        for (int off = 32; off > 0; off >>= 1) ls += __shfl_down(ls, off, 64);
        if ((tid & 63) == 0) red[tid >> 6] = ls;
        __syncthreads();
        float inv = 1.0f / (red[0] + red[1] + red[2] + red[3] + 1e-5f);
        for (int ci = 0; ci < 4; ci++)
            htb[((size_t)blk << 10) + tid + (ci << 8)] = f2b(v[ci] * inv);
    } else if (blk < 2 * B_ * P_) {
        int m = blk - B_ * P_; int b = m >> 9;
        int eh = hts[m * 2 + 0], et = hts[m * 2 + 1];
        const float* sh = enth + (size_t)(b * E_ + eh) * DNT_;
        const float* st = enth + (size_t)(b * E_ + et) * DNT_;
        for (int k = tid; k < DNT_; k += 256) {
            Xh[(size_t)m * KHT_ + k] = f2b(sh[k]);
            Xt[(size_t)m * KHT_ + k] = f2b(st[k]);
        }
    } else {
        int t = blk - 2 * B_ * P_;               // 256 blocks zero 1 MB
        ((float4*)logitsF)[(size_t)t * 256 + tid] = make_float4(0.f, 0.f, 0.f, 0.f);
    }
}

// ---------------------------------------------------------------------------
// bf16 MFMA GEMM, 64x64 tile, 4 waves 2x2, K-step 32, LDS staging (coalesced),
// register prefetch.
// zmode 0 (rs): z = batch; epilogue writes bf16 into Xh/Xt cols DNT_+n.
// zmode 1 (ht): z = mat (0=head,1=tail); epilogue bf16 tanh(acc+bias) -> oY.
__global__ __launch_bounds__(256) void k_gemm(
    const unsigned short* __restrict__ A0, const unsigned short* __restrict__ A1,
    const unsigned short* __restrict__ B0, const unsigned short* __restrict__ B1,
    long long lda, long long ldb, long long sAz, long long sBz,
    int nsteps, int zmode,
    const void* __restrict__ bias0, const void* __restrict__ bias1,
    unsigned short* __restrict__ oY0, unsigned short* __restrict__ oY1,
    unsigned short* __restrict__ oX1, unsigned short* __restrict__ oX2,
    const void* __restrict__ seq)
{
    int n0 = blockIdx.x * 64, m0 = blockIdx.y * 64, z = blockIdx.z;
    const unsigned short* Ab; const unsigned short* Bb;
    unsigned short* oY = nullptr; const void* bias = nullptr;
    if (zmode == 0) {
        Ab = A0 + (size_t)z * sAz; Bb = B0 + (size_t)z * sBz;
    } else {
        Ab = z ? A1 : A0; Bb = z ? B1 : B0;
        oY = z ? oY1 : oY0; bias = z ? bias1 : bias0;
    }
    __shared__ __align__(16) unsigned short a_lds[64][40];
    __shared__ __align__(16) unsigned short b_lds[64][40];
    int tid = threadIdx.x, lane = tid & 63, w = tid >> 6;
    int wm = (w >> 1) * 32, wn = (w & 1) * 32, q = lane >> 4, l15 = lane & 15;
    f32x4 acc00 = {0.f,0.f,0.f,0.f}, acc01 = acc00, acc10 = acc00, acc11 = acc00;
    int srow = tid >> 2, sch = (tid & 3) * 8;
    const unsigned short* pa = Ab + (size_t)(m0 + srow) * lda + sch;
    const unsigned short* pb = Bb + (size_t)(n0 + srow) * ldb + sch;
    int4 ra = *(const int4*)pa;
    int4 rb = *(const int4*)pb;
    for (int ks = 0; ks < nsteps; ks++) {
        __syncthreads();
        *(int4*)&a_lds[srow][sch] = ra;
        *(int4*)&b_lds[srow][sch] = rb;
        __syncthreads();
        if (ks + 1 < nsteps) {
            ra = *(const int4*)(pa + (size_t)(ks + 1) * 32);
            rb = *(const int4*)(pb + (size_t)(ks + 1) * 32);
        }
        bf16x8 a0 = *(const bf16x8*)&a_lds[wm + l15][q * 8];
        bf16x8 a1 = *(const bf16x8*)&a_lds[wm + 16 + l15][q * 8];
        bf16x8 b0 = *(const bf16x8*)&b_lds[wn + l15][q * 8];
        bf16x8 b1 = *(const bf16x8*)&b_lds[wn + 16 + l15][q * 8];
        acc00 = __builtin_amdgcn_mfma_f32_16x16x32_bf16(a0, b0, acc00, 0, 0, 0);
        acc01 = __builtin_amdgcn_mfma_f32_16x16x32_bf16(a0, b1, acc01, 0, 0, 0);
        acc10 = __builtin_amdgcn_mfma_f32_16x16x32_bf16(a1, b0, acc10, 0, 0, 0);
        acc11 = __builtin_amdgcn_mfma_f32_16x16x32_bf16(a1, b1, acc11, 0, 0, 0);
    }
    f32x4 accs[2][2] = {{acc00, acc01}, {acc10, acc11}};
    int isf = (zmode == 1) ? probe_isf(seq) : 0;
#pragma unroll
    for (int mt = 0; mt < 2; mt++)
#pragma unroll
        for (int nt = 0; nt < 2; nt++) {
            int gmb = m0 + wm + mt * 16 + q * 4;
            int gn  = n0 + wn + nt * 16 + l15;
            if (zmode == 0) {
#pragma unroll
                for (int r = 0; r < 4; r++) {
                    unsigned short v = f2b(accs[mt][nt][r]);
                    size_t o = (size_t)(z * P_ + gmb + r) * KHT_ + DNT_ + gn;
                    oX1[o] = v; oX2[o] = v;
                }
            } else {
                float bv = ld_in(bias, gn, isf);
#pragma unroll
                for (int r = 0; r < 4; r++)
                    oY[(size_t)(gmb + r) * EMB_ + gn] = f2b(tanhf(accs[mt][nt][r] + bv));
            }
        }
}

// ---------------------------------------------------------------------------
// Grouped bilinear v4 (revert to R1's plain-VGPR W-load path + targeted fixes):
//   logits[m,n] = sum_i hs[m,i] * ( sum_j ts[m,j] * W[g,i,j,n] )
// R2's global_load_lds version streamed 430 MB from HBM (LDS-DMA fetches got
// ~zero cross-block cache reuse; plain loads of the same data cached at 98.6%).
// Reverted to plain bf16x8 W loads. Fixes vs R1 (122 us, latency-stalled,
// MfmaUtil 8.3%):
//  1. wave owns one 16-col n-subtile (8 waves x 16 = 128 n), computes all
//     4 m-subtiles -> ZERO duplicate W loads across waves (R1: 2x), and
//     2 x 16B W loads feed 8 MFMAs (R1: 4 x 16B).
//  2. distance-2 register prefetch, static even/odd slots (R1: distance-1).
//  3. i-range split in half -> 768 blocks = 3 blocks/CU (R1: 1.5) for TLP;
//     LDS only 4 KB so occupancy is wave-limited, not LDS-limited.
__global__ __launch_bounds__(512) void k_bil(
    const unsigned short* __restrict__ hsB, const unsigned short* __restrict__ tsB,
    const unsigned short* __restrict__ WtB, float* __restrict__ logitsF)
{
    // 768 blocks = 8 XCDs x 96; per XCD: 3 (g,ic) combos x 32 m-tiles
    // -> W working set per XCD = 3 x 512 KB = 1.5 MB (L2-fit).
    int bid = blockIdx.x;
    int lin = (bid & 7) * 96 + (bid >> 3);
    int mt  = lin & 31;            // m-tile  [0,32)
    int gic = lin >> 5;            // [0,24)
    int g   = gic >> 1;            // group   [0,12)
    int ic  = gic & 1;             // i-half  [0,2)
    int m0  = mt * 64;

    int tid = threadIdx.x, lane = tid & 63, w = tid >> 6;
    int q = lane >> 4, l15 = lane & 15;
    int ns = w * 16;               // wave-private n-subtile

    __shared__ __align__(16) unsigned short hsT[32][64];   // [i][m], 4 KB
    {
        int m = tid >> 3, i4 = (tid & 7) * 4;
        ushort4 hv = *(const ushort4*)&hsB[(size_t)(m0 + m) * EMB_ + g * 64 + ic * 32 + i4];
        hsT[i4 + 0][m] = hv.x; hsT[i4 + 1][m] = hv.y;
        hsT[i4 + 2][m] = hv.z; hsT[i4 + 3][m] = hv.w;
    }

    // ts A-fragments (invariant over i): 4 m-subtiles x 2 j-halves
    bf16x8 a[4][2];
#pragma unroll
    for (int ms = 0; ms < 4; ++ms)
#pragma unroll
        for (int jh = 0; jh < 2; ++jh)
            a[ms][jh] = *(const bf16x8*)&tsB[(size_t)(m0 + ms * 16 + l15) * EMB_
                                             + g * 64 + jh * 32 + q * 8];
    __syncthreads();

    const unsigned short* pw = WtB + (size_t)(ns + l15) * KBIL_ + g * 4096 + ic * 2048 + q * 8;

    f32x4 acc[4];
#pragma unroll
    for (int ms = 0; ms < 4; ++ms) acc[ms] = (f32x4){0.f, 0.f, 0.f, 0.f};
    const f32x4 zf = {0.f, 0.f, 0.f, 0.f};

    // dist-2 software pipeline, static even/odd register slots
    bf16x8 w0a = *(const bf16x8*)(pw);
    bf16x8 w0b = *(const bf16x8*)(pw + 32);
    bf16x8 w1a = *(const bf16x8*)(pw + 64);
    bf16x8 w1b = *(const bf16x8*)(pw + 96);

#define BIL_STEP(ii, wa_, wb_)                                                             \
    do {                                                                                   \
        int ipre = (ii) + 2 <= 31 ? (ii) + 2 : 31;                                         \
        bf16x8 na = *(const bf16x8*)(pw + (size_t)ipre * 64);                              \
        bf16x8 nb = *(const bf16x8*)(pw + (size_t)ipre * 64 + 32);                         \
        f32x4 p[4];                                                                        \
        _Pragma("unroll")                                                                  \
        for (int ms = 0; ms < 4; ++ms) {                                                   \
            f32x4 t = __builtin_amdgcn_mfma_f32_16x16x32_bf16(a[ms][0], wa_, zf, 0, 0, 0); \
            p[ms]   = __builtin_amdgcn_mfma_f32_16x16x32_bf16(a[ms][1], wb_, t, 0, 0, 0);  \
        }                                                                                  \
        _Pragma("unroll")                                                                  \
        for (int ms = 0; ms < 4; ++ms) {                                                   \
            ushort4 hv = *(const ushort4*)&hsT[ii][ms * 16 + q * 4];                       \
            acc[ms][0] += b2f(hv.x) * p[ms][0];                                            \
            acc[ms][1] += b2f(hv.y) * p[ms][1];                                            \
            acc[ms][2] += b2f(hv.z) * p[ms][2];                                            \
            acc[ms][3] += b2f(hv.w) * p[ms][3];                                            \
        }                                                                                  \
        wa_ = na; wb_ = nb;                                                                \
    } while (0)

#pragma unroll 4
    for (int ii = 0; ii < 16; ++ii) {
        BIL_STEP(2 * ii,     w0a, w0b);
        BIL_STEP(2 * ii + 1, w1a, w1b);
    }
#undef BIL_STEP

#pragma unroll
    for (int ms = 0; ms < 4; ++ms)
#pragma unroll
        for (int r = 0; r < 4; ++r)
            atomicAdd(&logitsF[(size_t)(m0 + ms * 16 + q * 4 + r) * NPAD_ + ns + l15],
                      acc[ms][r]);
}

// ---------------------------------------------------------------------------
// final: logits out with bias, n<97
__global__ __launch_bounds__(256) void k_fin(
    const float* __restrict__ logitsF, const void* __restrict__ b_bil,
    void* __restrict__ outv, const void* __restrict__ seq)
{
    int isf = probe_isf(seq);
    int idx = blockIdx.x * 256 + threadIdx.x;
    if (idx >= B_ * P_ * NL_) return;
    int m = idx / NL_, n = idx % NL_;
    st_out(outv, idx, logitsF[(size_t)m * NPAD_ + n] + ld_in(b_bil, n, isf), isf);
}

// ---------------------------------------------------------------------------
extern "C" void kernel_launch(void* const* d_in, const int* in_sizes, int n_in,
                              void* d_out, int out_size, void* d_ws, size_t ws_size,
                              hipStream_t stream)
{
    const void* seq    = d_in[0];
    const void* att    = d_in[1];
    const int*  epos   = (const int*)d_in[2];
    const int*  spos   = (const int*)d_in[3];
    const int*  vpos   = (const int*)d_in[4];
    const int*  hts    = (const int*)d_in[5];
    const void* ntype  = d_in[6];
    const void* W_head = d_in[7];
    const void* b_head = d_in[8];
    const void* W_tail = d_in[9];
    const void* b_tail = d_in[10];
    const void* W_bil  = d_in[11];
    const void* b_bil  = d_in[12];

    // output element offsets (dtype-agnostic)
    long long mention_off = (long long)B_ * P_ * NL_;
    long long sent_off    = mention_off + (long long)B_ * E_ * K_ * D_;
    long long virt_off    = sent_off + (long long)B_ * S_ * D_;

    // workspace carve (~50 MB)
    char* p = (char*)d_ws;
    auto alloc = [&](size_t bytes) { void* r = (void*)p; p += (bytes + 255) & ~(size_t)255; return r; };
    unsigned short* e_att   = (unsigned short*)alloc((size_t)B_ * E_ * H_ * C_ * 2);
    unsigned short* htb     = (unsigned short*)alloc((size_t)B_ * P_ * C_ * 2);
    unsigned short* seqT    = (unsigned short*)alloc((size_t)B_ * D_ * C_ * 2);
    unsigned short* WtH     = (unsigned short*)alloc((size_t)EMB_ * KHT_ * 2);
    unsigned short* WtT     = (unsigned short*)alloc((size_t)EMB_ * KHT_ * 2);
    unsigned short* WtB     = (unsigned short*)alloc((size_t)NPAD_ * KBIL_ * 2);
    unsigned short* Xh      = (unsigned short*)alloc((size_t)B_ * P_ * KHT_ * 2);
    unsigned short* Xt      = (unsigned short*)alloc((size_t)B_ * P_ * KHT_ * 2);
    unsigned short* hsB     = (unsigned short*)alloc((size_t)B_ * P_ * EMB_ * 2);
    unsigned short* tsB     = (unsigned short*)alloc((size_t)B_ * P_ * EMB_ * 2);
    float*          logitsF = (float*)alloc((size_t)B_ * P_ * NPAD_ * 4);
    float*          enth    = (float*)alloc((size_t)B_ * E_ * DNT_ * 4);

    dim3 blk(256);
    k_prep<<<PREP_TBIL, blk, 0, stream>>>(
        seq, att, epos, spos, vpos, ntype, W_head, W_tail, W_bil,
        enth, e_att, seqT, WtH, WtT, WtB,
        d_out, mention_off, sent_off, virt_off);
    k_mid<<<2 * B_ * P_ + 256, blk, 0, stream>>>(e_att, enth, hts, htb, Xh, Xt, logitsF);
    // rs GEMM: per batch [512 x 1024] @ [1024 x 768]^T -> X cols 1024..1791
    k_gemm<<<dim3(EMB_ / 64, P_ / 64, B_), blk, 0, stream>>>(
        htb, nullptr, seqT, nullptr, C_, C_,
        (long long)P_ * C_, (long long)D_ * C_, C_ / 32, 0,
        nullptr, nullptr, nullptr, nullptr, Xh, Xt, seq);
    // fused head+tail: [2048 x 1792] @ [1792 x 768]^T, tanh+bias -> bf16 hsB/tsB
    k_gemm<<<dim3(EMB_ / 64, (B_ * P_) / 64, 2), blk, 0, stream>>>(
        Xh, Xt, WtH, WtT, KHT_, KHT_, 0, 0, KHT_ / 32, 1,
        b_head, b_tail, hsB, tsB, nullptr, nullptr, seq);
    // bilinear v4: 768 blocks (32 m-tiles x 12 g x 2 i-halves), XCD-affine
    k_bil<<<dim3(768), dim3(512), 0, stream>>>(hsB, tsB, WtB, logitsF);
    k_fin<<<(B_ * P_ * NL_ + 255) / 256, blk, 0, stream>>>(logitsF, b_bil, d_out, seq);
}

// Round 4
// 408.291 us; speedup vs baseline: 1.8592x; 1.0109x over previous
//
#include <hip/hip_runtime.h>

// Problem constants (GCN_61065845014917)
#define B_   4
#define C_   1024
#define D_   768
#define H_   12
#define E_   32
#define K_   2
#define S_   24
#define V_   8
#define P_   512
#define NT_  256
#define EMB_ 768
#define BLK_ 64
#define NL_  97
#define DNT_ 1024     // D+NT
#define KHT_ 1792     // 2D+NT
#define KBIL_ 49152   // EMB*BLK
#define NPAD_ 128     // NL padded for MFMA
#define NGIC_ 24      // bilinear partial slabs (12 g x 2 i-halves)

typedef __bf16 bf16x8 __attribute__((ext_vector_type(8)));
typedef float  f32x4  __attribute__((ext_vector_type(4)));

__device__ __forceinline__ float b2f(unsigned short u) {
    return (float)__builtin_bit_cast(__bf16, u);
}
__device__ __forceinline__ unsigned short f2b(float f) {
    return __builtin_bit_cast(unsigned short, (__bf16)f);   // RNE
}
// dtype-dispatched input load / output store (isf=1: f32 buffers, isf=0: bf16)
__device__ __forceinline__ float ld_in(const void* p, size_t i, int isf) {
    return isf ? ((const float*)p)[i] : b2f(((const unsigned short*)p)[i]);
}
__device__ __forceinline__ void st_out(void* p, size_t i, float v, int isf) {
    if (isf) ((float*)p)[i] = v;
    else     ((unsigned short*)p)[i] = f2b(v);
}
// per-wave inline dtype probe: 64 even-index ushorts of sequence_output.
__device__ __forceinline__ int probe_isf(const void* seq) {
    unsigned short u = ((const unsigned short*)seq)[2 * (threadIdx.x & 63)];
    int huge = !(fabsf(b2f(u)) <= 1e10f);          // catches NaN
    unsigned long long zb = __ballot(u == 0);
    return __any(huge) || (__popcll(zb) > 56);
}

// ---------------------------------------------------------------------------
// K1 fused prep: [0,256) gather, [256,1792) eatt, [1792,2560) t_seq,
//                [2560,3232) t_w, [3232,4000) t_bil(64k/blk)
#define PREP_GATHER 256
#define PREP_EATT   (PREP_GATHER + B_*E_*H_)     // +1536 -> 1792
#define PREP_TSEQ   (PREP_EATT + 768)            // -> 2560
#define PREP_TW     (PREP_TSEQ + 672)            // -> 3232
#define PREP_TBIL   (PREP_TW + 768)              // -> 4000

__global__ __launch_bounds__(256) void k_prep(
    const void* __restrict__ seq, const void* __restrict__ att,
    const int* __restrict__ epos, const int* __restrict__ spos,
    const int* __restrict__ vpos, const void* __restrict__ ntype,
    const void* __restrict__ Wh, const void* __restrict__ Wt_,
    const void* __restrict__ Wb,
    float* __restrict__ enth, unsigned short* __restrict__ e_att,
    unsigned short* __restrict__ seqT,
    unsigned short* __restrict__ WtH, unsigned short* __restrict__ WtT,
    unsigned short* __restrict__ WtB,
    void* __restrict__ outv, long long moff, long long soff, long long voff)
{
    __shared__ __align__(16) unsigned char smem[12544];
    int blk = blockIdx.x, tid = threadIdx.x;
    int isf = probe_isf(seq);
    if (blk < PREP_GATHER) {
        if (blk < B_ * E_) {
            int b = blk / E_, e = blk % E_;
            int i0 = epos[(b * E_ + e) * K_ + 0] + 1;
            int i1 = epos[(b * E_ + e) * K_ + 1] + 1;
            size_t r0 = ((size_t)b * C_ + i0) * D_;
            size_t r1 = ((size_t)b * C_ + i1) * D_;
            size_t m0 = (size_t)moff + ((size_t)(b * E_ * K_) + 2 * e) * D_;
            size_t m1 = m0 + D_;
            float* eh = enth + (size_t)(b * E_ + e) * DNT_;
            for (int d = tid; d < D_; d += 256) {
                float a = ld_in(seq, r0 + d, isf);
                float c = ld_in(seq, r1 + d, isf);
                st_out(outv, m0 + d, a, isf);
                st_out(outv, m1 + d, c, isf);
                float mx = fmaxf(a, c);
                eh[d] = mx + logf(expf(a - mx) + expf(c - mx));
            }
            size_t nt0 = (size_t)(b * E_ + e) * NT_;
            for (int j = tid; j < NT_; j += 256) eh[D_ + j] = ld_in(ntype, nt0 + j, isf);
        } else if (blk < B_ * E_ + B_ * S_) {
            int t = blk - B_ * E_; int b = t / S_, s = t % S_;
            int i = spos[b * S_ + s] + 1;
            size_t r = ((size_t)b * C_ + i) * D_;
            size_t o = (size_t)soff + (size_t)(b * S_ + s) * D_;
            for (int d = tid; d < D_; d += 256) st_out(outv, o + d, ld_in(seq, r + d, isf), isf);
        } else {
            int t = blk - B_ * E_ - B_ * S_; int b = t / V_, v = t % V_;
            int i = vpos[b * V_ + v] + 1;
            size_t r = ((size_t)b * C_ + i) * D_;
            size_t o = (size_t)voff + (size_t)(b * V_ + v) * D_;
            for (int d = tid; d < D_; d += 256) st_out(outv, o + d, ld_in(seq, r + d, isf), isf);
        }
    } else if (blk < PREP_EATT) {
        int t = blk - PREP_GATHER;
        int b = t / (E_ * H_); int r = t % (E_ * H_); int e = r / H_; int h = r % H_;
        int i0 = epos[(b * E_ + e) * K_ + 0] + 1;
        int i1 = epos[(b * E_ + e) * K_ + 1] + 1;
        size_t a0 = (((size_t)b * H_ + h) * C_ + i0) * C_;
        size_t a1 = (((size_t)b * H_ + h) * C_ + i1) * C_;
        unsigned short* o = e_att + (((size_t)(b * E_ + e)) * H_ + h) * C_;
        for (int c = tid; c < C_; c += 256)
            o[c] = f2b(0.5f * (ld_in(att, a0 + c, isf) + ld_in(att, a1 + c, isf)));
    } else if (blk < PREP_TSEQ) {
        int t = blk - PREP_EATT;                 // b*192 + ct*12 + dt
        int b = t / 192; int r = t % 192; int ct = r / 12; int dt = r % 12;
        typedef unsigned short row65[65];
        row65* tile = (row65*)smem;
        for (int idx = tid; idx < 4096; idx += 256) {
            int cc = idx >> 6, dd = idx & 63;
            tile[cc][dd] = f2b(ld_in(seq, ((size_t)b * C_ + ct * 64 + cc) * D_ + dt * 64 + dd, isf));
        }
        __syncthreads();
        for (int idx = tid; idx < 4096; idx += 256) {
            int dd = idx >> 6, cc = idx & 63;
            seqT[((size_t)b * D_ + dt * 64 + dd) * C_ + ct * 64 + cc] = tile[cc][dd];
        }
    } else if (blk < PREP_TW) {
        int t = blk - PREP_TSEQ;                 // mat*336 + kt*12 + nt
        int mat = t / 336; int r = t % 336; int kt = r / 12; int nt = r % 12;
        const void* in = mat ? Wt_ : Wh;
        unsigned short* out = mat ? WtT : WtH;
        typedef unsigned short row65[65];
        row65* tile = (row65*)smem;
        for (int idx = tid; idx < 4096; idx += 256) {
            int kk = idx >> 6, nn = idx & 63;
            tile[kk][nn] = f2b(ld_in(in, ((size_t)kt * 64 + kk) * EMB_ + nt * 64 + nn, isf));
        }
        __syncthreads();
        for (int idx = tid; idx < 4096; idx += 256) {
            int nn = idx >> 6, kk = idx & 63;
            out[((size_t)nt * 64 + nn) * KHT_ + kt * 64 + kk] = tile[kk][nn];
        }
    } else {
        int t = blk - PREP_TW;                   // 64 k-cols per block
        int k0 = t << 6;
        unsigned short* raw = (unsigned short*)smem;   // [64*97]
        for (int idx = tid; idx < 64 * NL_; idx += 256)
            raw[idx] = f2b(ld_in(Wb, (size_t)k0 * NL_ + idx, isf));
        __syncthreads();
        int kk = tid & 63, nq = tid >> 6;              // 4 quarters x 32 n
        for (int i = 0; i < 32; i++) {
            int n = nq * 32 + i;
            unsigned short v = (n < NL_) ? raw[kk * NL_ + n] : (unsigned short)0;
            WtB[(size_t)n * KBIL_ + k0 + kk] = v;
        }
    }
}

// ---------------------------------------------------------------------------
// K2 fused mid: [0,2048) htatt, [2048,4096) xbuild
__global__ __launch_bounds__(256) void k_mid(
    const unsigned short* __restrict__ e_att, const float* __restrict__ enth,
    const int* __restrict__ hts,
    unsigned short* __restrict__ htb,
    unsigned short* __restrict__ Xh, unsigned short* __restrict__ Xt)
{
    __shared__ float red[4];
    int blk = blockIdx.x, tid = threadIdx.x;
    if (blk < B_ * P_) {
        int b = blk >> 9;
        int he = hts[blk * 2 + 0], te = hts[blk * 2 + 1];
        const unsigned short* ph = e_att + (size_t)(b * E_ + he) * H_ * C_;
        const unsigned short* pt = e_att + (size_t)(b * E_ + te) * H_ * C_;
        float v[4]; float ls = 0.f;
        for (int ci = 0; ci < 4; ci++) {
            int c = tid + (ci << 8);
            float acc = 0.f;
#pragma unroll
            for (int h = 0; h < H_; h++) acc += b2f(ph[h * C_ + c]) * b2f(pt[h * C_ + c]);
            acc *= (1.0f / (float)H_);
            v[ci] = acc; ls += acc;
        }
        for (int off = 32; off > 0; off >>= 1) ls += __shfl_down(ls, off, 64);
        if ((tid & 63) == 0) red[tid >> 6] = ls;
        __syncthreads();
        float inv = 1.0f / (red[0] + red[1] + red[2] + red[3] + 1e-5f);
        for (int ci = 0; ci < 4; ci++)
            htb[((size_t)blk << 10) + tid + (ci << 8)] = f2b(v[ci] * inv);
    } else {
        int m = blk - B_ * P_; int b = m >> 9;
        int eh = hts[m * 2 + 0], et = hts[m * 2 + 1];
        const float* sh = enth + (size_t)(b * E_ + eh) * DNT_;
        const float* st = enth + (size_t)(b * E_ + et) * DNT_;
        for (int k = tid; k < DNT_; k += 256) {
            Xh[(size_t)m * KHT_ + k] = f2b(sh[k]);
            Xt[(size_t)m * KHT_ + k] = f2b(st[k]);
        }
    }
}

// ---------------------------------------------------------------------------
// bf16 MFMA GEMM, 64x64 tile, 4 waves 2x2, K-step 32, LDS staging (coalesced),
// register prefetch.
// zmode 0 (rs): z = batch; epilogue writes bf16 into Xh/Xt cols DNT_+n.
// zmode 1 (ht): z = mat (0=head,1=tail); epilogue bf16 tanh(acc+bias) -> oY.
__global__ __launch_bounds__(256) void k_gemm(
    const unsigned short* __restrict__ A0, const unsigned short* __restrict__ A1,
    const unsigned short* __restrict__ B0, const unsigned short* __restrict__ B1,
    long long lda, long long ldb, long long sAz, long long sBz,
    int nsteps, int zmode,
    const void* __restrict__ bias0, const void* __restrict__ bias1,
    unsigned short* __restrict__ oY0, unsigned short* __restrict__ oY1,
    unsigned short* __restrict__ oX1, unsigned short* __restrict__ oX2,
    const void* __restrict__ seq)
{
    int n0 = blockIdx.x * 64, m0 = blockIdx.y * 64, z = blockIdx.z;
    const unsigned short* Ab; const unsigned short* Bb;
    unsigned short* oY = nullptr; const void* bias = nullptr;
    if (zmode == 0) {
        Ab = A0 + (size_t)z * sAz; Bb = B0 + (size_t)z * sBz;
    } else {
        Ab = z ? A1 : A0; Bb = z ? B1 : B0;
        oY = z ? oY1 : oY0; bias = z ? bias1 : bias0;
    }
    __shared__ __align__(16) unsigned short a_lds[64][40];
    __shared__ __align__(16) unsigned short b_lds[64][40];
    int tid = threadIdx.x, lane = tid & 63, w = tid >> 6;
    int wm = (w >> 1) * 32, wn = (w & 1) * 32, q = lane >> 4, l15 = lane & 15;
    f32x4 acc00 = {0.f,0.f,0.f,0.f}, acc01 = acc00, acc10 = acc00, acc11 = acc00;
    int srow = tid >> 2, sch = (tid & 3) * 8;
    const unsigned short* pa = Ab + (size_t)(m0 + srow) * lda + sch;
    const unsigned short* pb = Bb + (size_t)(n0 + srow) * ldb + sch;
    int4 ra = *(const int4*)pa;
    int4 rb = *(const int4*)pb;
    for (int ks = 0; ks < nsteps; ks++) {
        __syncthreads();
        *(int4*)&a_lds[srow][sch] = ra;
        *(int4*)&b_lds[srow][sch] = rb;
        __syncthreads();
        if (ks + 1 < nsteps) {
            ra = *(const int4*)(pa + (size_t)(ks + 1) * 32);
            rb = *(const int4*)(pb + (size_t)(ks + 1) * 32);
        }
        bf16x8 a0 = *(const bf16x8*)&a_lds[wm + l15][q * 8];
        bf16x8 a1 = *(const bf16x8*)&a_lds[wm + 16 + l15][q * 8];
        bf16x8 b0 = *(const bf16x8*)&b_lds[wn + l15][q * 8];
        bf16x8 b1 = *(const bf16x8*)&b_lds[wn + 16 + l15][q * 8];
        acc00 = __builtin_amdgcn_mfma_f32_16x16x32_bf16(a0, b0, acc00, 0, 0, 0);
        acc01 = __builtin_amdgcn_mfma_f32_16x16x32_bf16(a0, b1, acc01, 0, 0, 0);
        acc10 = __builtin_amdgcn_mfma_f32_16x16x32_bf16(a1, b0, acc10, 0, 0, 0);
        acc11 = __builtin_amdgcn_mfma_f32_16x16x32_bf16(a1, b1, acc11, 0, 0, 0);
    }
    f32x4 accs[2][2] = {{acc00, acc01}, {acc10, acc11}};
    int isf = (zmode == 1) ? probe_isf(seq) : 0;
#pragma unroll
    for (int mt = 0; mt < 2; mt++)
#pragma unroll
        for (int nt = 0; nt < 2; nt++) {
            int gmb = m0 + wm + mt * 16 + q * 4;
            int gn  = n0 + wn + nt * 16 + l15;
            if (zmode == 0) {
#pragma unroll
                for (int r = 0; r < 4; r++) {
                    unsigned short v = f2b(accs[mt][nt][r]);
                    size_t o = (size_t)(z * P_ + gmb + r) * KHT_ + DNT_ + gn;
                    oX1[o] = v; oX2[o] = v;
                }
            } else {
                float bv = ld_in(bias, gn, isf);
#pragma unroll
                for (int r = 0; r < 4; r++)
                    oY[(size_t)(gmb + r) * EMB_ + gn] = f2b(tanhf(accs[mt][nt][r] + bv));
            }
        }
}

// ---------------------------------------------------------------------------
// Grouped bilinear v5: v4's plain-VGPR dedup'd loads + dist-2 prefetch, with
// the atomic epilogue replaced by conflict-free per-(g,ic) partial slabs.
// R3 post-mortem: k_bil ~75 us vs ~10 us issue floor; the 6.3M device-scope
// f32 atomicAdds (24 blocks per output cell, near-simultaneous) are the only
// structural serializer left -> plain stores to logitsP[gic], reduced in k_fin.
__global__ __launch_bounds__(512) void k_bil(
    const unsigned short* __restrict__ hsB, const unsigned short* __restrict__ tsB,
    const unsigned short* __restrict__ WtB, float* __restrict__ logitsP)
{
    // 768 blocks = 8 XCDs x 96; per XCD: 3 (g,ic) combos x 32 m-tiles
    // -> W working set per XCD = 3 x 512 KB = 1.5 MB (L2-fit).
    int bid = blockIdx.x;
    int lin = (bid & 7) * 96 + (bid >> 3);
    int mt  = lin & 31;            // m-tile  [0,32)
    int gic = lin >> 5;            // [0,24)  (also the partial-slab index)
    int g   = gic >> 1;            // group   [0,12)
    int ic  = gic & 1;             // i-half  [0,2)
    int m0  = mt * 64;

    int tid = threadIdx.x, lane = tid & 63, w = tid >> 6;
    int q = lane >> 4, l15 = lane & 15;
    int ns = w * 16;               // wave-private n-subtile

    __shared__ __align__(16) unsigned short hsT[32][64];   // [i][m], 4 KB
    {
        int m = tid >> 3, i4 = (tid & 7) * 4;
        ushort4 hv = *(const ushort4*)&hsB[(size_t)(m0 + m) * EMB_ + g * 64 + ic * 32 + i4];
        hsT[i4 + 0][m] = hv.x; hsT[i4 + 1][m] = hv.y;
        hsT[i4 + 2][m] = hv.z; hsT[i4 + 3][m] = hv.w;
    }

    // ts A-fragments (invariant over i): 4 m-subtiles x 2 j-halves
    bf16x8 a[4][2];
#pragma unroll
    for (int ms = 0; ms < 4; ++ms)
#pragma unroll
        for (int jh = 0; jh < 2; ++jh)
            a[ms][jh] = *(const bf16x8*)&tsB[(size_t)(m0 + ms * 16 + l15) * EMB_
                                             + g * 64 + jh * 32 + q * 8];
    __syncthreads();

    const unsigned short* pw = WtB + (size_t)(ns + l15) * KBIL_ + g * 4096 + ic * 2048 + q * 8;

    f32x4 acc[4];
#pragma unroll
    for (int ms = 0; ms < 4; ++ms) acc[ms] = (f32x4){0.f, 0.f, 0.f, 0.f};
    const f32x4 zf = {0.f, 0.f, 0.f, 0.f};

    // dist-2 software pipeline, static even/odd register slots
    bf16x8 w0a = *(const bf16x8*)(pw);
    bf16x8 w0b = *(const bf16x8*)(pw + 32);
    bf16x8 w1a = *(const bf16x8*)(pw + 64);
    bf16x8 w1b = *(const bf16x8*)(pw + 96);

#define BIL_STEP(ii, wa_, wb_)                                                             \
    do {                                                                                   \
        int ipre = (ii) + 2 <= 31 ? (ii) + 2 : 31;                                         \
        bf16x8 na = *(const bf16x8*)(pw + (size_t)ipre * 64);                              \
        bf16x8 nb = *(const bf16x8*)(pw + (size_t)ipre * 64 + 32);                         \
        f32x4 p[4];                                                                        \
        _Pragma("unroll")                                                                  \
        for (int ms = 0; ms < 4; ++ms) {                                                   \
            f32x4 t = __builtin_amdgcn_mfma_f32_16x16x32_bf16(a[ms][0], wa_, zf, 0, 0, 0); \
            p[ms]   = __builtin_amdgcn_mfma_f32_16x16x32_bf16(a[ms][1], wb_, t, 0, 0, 0);  \
        }                                                                                  \
        _Pragma("unroll")                                                                  \
        for (int ms = 0; ms < 4; ++ms) {                                                   \
            ushort4 hv = *(const ushort4*)&hsT[ii][ms * 16 + q * 4];                       \
            acc[ms][0] += b2f(hv.x) * p[ms][0];                                            \
            acc[ms][1] += b2f(hv.y) * p[ms][1];                                            \
            acc[ms][2] += b2f(hv.z) * p[ms][2];                                            \
            acc[ms][3] += b2f(hv.w) * p[ms][3];                                            \
        }                                                                                  \
        wa_ = na; wb_ = nb;                                                                \
    } while (0)

#pragma unroll 4
    for (int ii = 0; ii < 16; ++ii) {
        BIL_STEP(2 * ii,     w0a, w0b);
        BIL_STEP(2 * ii + 1, w1a, w1b);
    }
#undef BIL_STEP

    // conflict-free epilogue: each (mt,gic) block owns its [64][128] region
    float* outp = logitsP + ((size_t)gic * (B_ * P_) + m0) * NPAD_ + ns + l15;
#pragma unroll
    for (int ms = 0; ms < 4; ++ms)
#pragma unroll
        for (int r = 0; r < 4; ++r)
            outp[(size_t)(ms * 16 + q * 4 + r) * NPAD_] = acc[ms][r];
}

// ---------------------------------------------------------------------------
// final: reduce 24 bilinear partials + bias, n<97
__global__ __launch_bounds__(256) void k_fin(
    const float* __restrict__ logitsP, const void* __restrict__ b_bil,
    void* __restrict__ outv, const void* __restrict__ seq)
{
    int isf = probe_isf(seq);
    int idx = blockIdx.x * 256 + threadIdx.x;
    if (idx >= B_ * P_ * NL_) return;
    int m = idx / NL_, n = idx % NL_;
    float s = ld_in(b_bil, n, isf);
#pragma unroll
    for (int p = 0; p < NGIC_; ++p)
        s += logitsP[((size_t)p * (B_ * P_) + m) * NPAD_ + n];
    st_out(outv, idx, s, isf);
}

// ---------------------------------------------------------------------------
extern "C" void kernel_launch(void* const* d_in, const int* in_sizes, int n_in,
                              void* d_out, int out_size, void* d_ws, size_t ws_size,
                              hipStream_t stream)
{
    const void* seq    = d_in[0];
    const void* att    = d_in[1];
    const int*  epos   = (const int*)d_in[2];
    const int*  spos   = (const int*)d_in[3];
    const int*  vpos   = (const int*)d_in[4];
    const int*  hts    = (const int*)d_in[5];
    const void* ntype  = d_in[6];
    const void* W_head = d_in[7];
    const void* b_head = d_in[8];
    const void* W_tail = d_in[9];
    const void* b_tail = d_in[10];
    const void* W_bil  = d_in[11];
    const void* b_bil  = d_in[12];

    // output element offsets (dtype-agnostic)
    long long mention_off = (long long)B_ * P_ * NL_;
    long long sent_off    = mention_off + (long long)B_ * E_ * K_ * D_;
    long long virt_off    = sent_off + (long long)B_ * S_ * D_;

    // workspace carve (~75 MB)
    char* p = (char*)d_ws;
    auto alloc = [&](size_t bytes) { void* r = (void*)p; p += (bytes + 255) & ~(size_t)255; return r; };
    unsigned short* e_att   = (unsigned short*)alloc((size_t)B_ * E_ * H_ * C_ * 2);
    unsigned short* htb     = (unsigned short*)alloc((size_t)B_ * P_ * C_ * 2);
    unsigned short* seqT    = (unsigned short*)alloc((size_t)B_ * D_ * C_ * 2);
    unsigned short* WtH     = (unsigned short*)alloc((size_t)EMB_ * KHT_ * 2);
    unsigned short* WtT     = (unsigned short*)alloc((size_t)EMB_ * KHT_ * 2);
    unsigned short* WtB     = (unsigned short*)alloc((size_t)NPAD_ * KBIL_ * 2);
    unsigned short* Xh      = (unsigned short*)alloc((size_t)B_ * P_ * KHT_ * 2);
    unsigned short* Xt      = (unsigned short*)alloc((size_t)B_ * P_ * KHT_ * 2);
    unsigned short* hsB     = (unsigned short*)alloc((size_t)B_ * P_ * EMB_ * 2);
    unsigned short* tsB     = (unsigned short*)alloc((size_t)B_ * P_ * EMB_ * 2);
    float*          logitsP = (float*)alloc((size_t)NGIC_ * B_ * P_ * NPAD_ * 4);  // 24 MB
    float*          enth    = (float*)alloc((size_t)B_ * E_ * DNT_ * 4);

    dim3 blk(256);
    k_prep<<<PREP_TBIL, blk, 0, stream>>>(
        seq, att, epos, spos, vpos, ntype, W_head, W_tail, W_bil,
        enth, e_att, seqT, WtH, WtT, WtB,
        d_out, mention_off, sent_off, virt_off);
    k_mid<<<2 * B_ * P_, blk, 0, stream>>>(e_att, enth, hts, htb, Xh, Xt);
    // rs GEMM: per batch [512 x 1024] @ [1024 x 768]^T -> X cols 1024..1791
    k_gemm<<<dim3(EMB_ / 64, P_ / 64, B_), blk, 0, stream>>>(
        htb, nullptr, seqT, nullptr, C_, C_,
        (long long)P_ * C_, (long long)D_ * C_, C_ / 32, 0,
        nullptr, nullptr, nullptr, nullptr, Xh, Xt, seq);
    // fused head+tail: [2048 x 1792] @ [1792 x 768]^T, tanh+bias -> bf16 hsB/tsB
    k_gemm<<<dim3(EMB_ / 64, (B_ * P_) / 64, 2), blk, 0, stream>>>(
        Xh, Xt, WtH, WtT, KHT_, KHT_, 0, 0, KHT_ / 32, 1,
        b_head, b_tail, hsB, tsB, nullptr, nullptr, seq);
    // bilinear v5: 768 blocks (32 m-tiles x 12 g x 2 i-halves), XCD-affine,
    // conflict-free partial-slab epilogue (no atomics)
    k_bil<<<dim3(768), dim3(512), 0, stream>>>(hsB, tsB, WtB, logitsP);
    k_fin<<<(B_ * P_ * NL_ + 255) / 256, blk, 0, stream>>>(logitsP, b_bil, d_out, seq);
}

// Round 5
// 387.559 us; speedup vs baseline: 1.9586x; 1.0535x over previous
//
#include <hip/hip_runtime.h>

// Problem constants (GCN_61065845014917)
#define B_   4
#define C_   1024
#define D_   768
#define H_   12
#define E_   32
#define K_   2
#define S_   24
#define V_   8
#define P_   512
#define NT_  256
#define EMB_ 768
#define BLK_ 64
#define NL_  97
#define DNT_ 1024     // D+NT
#define KHT_ 1792     // 2D+NT
#define KBIL_ 49152   // EMB*BLK
#define NPAD_ 128     // NL padded for MFMA
#define NGIC_ 24      // bilinear partial slabs (12 g x 2 i-halves)

typedef __bf16 bf16x8 __attribute__((ext_vector_type(8)));
typedef float  f32x4  __attribute__((ext_vector_type(4)));

__device__ __forceinline__ float b2f(unsigned short u) {
    return (float)__builtin_bit_cast(__bf16, u);
}
__device__ __forceinline__ unsigned short f2b(float f) {
    return __builtin_bit_cast(unsigned short, (__bf16)f);   // RNE
}
// dtype-dispatched input load / output store (isf=1: f32 buffers, isf=0: bf16)
__device__ __forceinline__ float ld_in(const void* p, size_t i, int isf) {
    return isf ? ((const float*)p)[i] : b2f(((const unsigned short*)p)[i]);
}
__device__ __forceinline__ void st_out(void* p, size_t i, float v, int isf) {
    if (isf) ((float*)p)[i] = v;
    else     ((unsigned short*)p)[i] = f2b(v);
}
// per-wave inline dtype probe: 64 even-index ushorts of sequence_output.
__device__ __forceinline__ int probe_isf(const void* seq) {
    unsigned short u = ((const unsigned short*)seq)[2 * (threadIdx.x & 63)];
    int huge = !(fabsf(b2f(u)) <= 1e10f);          // catches NaN
    unsigned long long zb = __ballot(u == 0);
    return __any(huge) || (__popcll(zb) > 56);
}

// ---------------------------------------------------------------------------
// K1 fused prep: [0,256) gather, [256,1792) eatt, [1792,2560) t_seq,
//                [2560,3232) t_w, [3232,4000) t_bil(fragment-order W2)
#define PREP_GATHER 256
#define PREP_EATT   (PREP_GATHER + B_*E_*H_)     // +1536 -> 1792
#define PREP_TSEQ   (PREP_EATT + 768)            // -> 2560
#define PREP_TW     (PREP_TSEQ + 672)            // -> 3232
#define PREP_TBIL   (PREP_TW + 768)              // -> 4000

__global__ __launch_bounds__(256) void k_prep(
    const void* __restrict__ seq, const void* __restrict__ att,
    const int* __restrict__ epos, const int* __restrict__ spos,
    const int* __restrict__ vpos, const void* __restrict__ ntype,
    const void* __restrict__ Wh, const void* __restrict__ Wt_,
    const void* __restrict__ Wb,
    float* __restrict__ enth, unsigned short* __restrict__ e_att,
    unsigned short* __restrict__ seqT,
    unsigned short* __restrict__ WtH, unsigned short* __restrict__ WtT,
    unsigned short* __restrict__ WtB,
    void* __restrict__ outv, long long moff, long long soff, long long voff)
{
    __shared__ __align__(16) unsigned char smem[12544];
    int blk = blockIdx.x, tid = threadIdx.x;
    int isf = probe_isf(seq);
    if (blk < PREP_GATHER) {
        if (blk < B_ * E_) {
            int b = blk / E_, e = blk % E_;
            int i0 = epos[(b * E_ + e) * K_ + 0] + 1;
            int i1 = epos[(b * E_ + e) * K_ + 1] + 1;
            size_t r0 = ((size_t)b * C_ + i0) * D_;
            size_t r1 = ((size_t)b * C_ + i1) * D_;
            size_t m0 = (size_t)moff + ((size_t)(b * E_ * K_) + 2 * e) * D_;
            size_t m1 = m0 + D_;
            float* eh = enth + (size_t)(b * E_ + e) * DNT_;
            for (int d = tid; d < D_; d += 256) {
                float a = ld_in(seq, r0 + d, isf);
                float c = ld_in(seq, r1 + d, isf);
                st_out(outv, m0 + d, a, isf);
                st_out(outv, m1 + d, c, isf);
                float mx = fmaxf(a, c);
                eh[d] = mx + logf(expf(a - mx) + expf(c - mx));
            }
            size_t nt0 = (size_t)(b * E_ + e) * NT_;
            for (int j = tid; j < NT_; j += 256) eh[D_ + j] = ld_in(ntype, nt0 + j, isf);
        } else if (blk < B_ * E_ + B_ * S_) {
            int t = blk - B_ * E_; int b = t / S_, s = t % S_;
            int i = spos[b * S_ + s] + 1;
            size_t r = ((size_t)b * C_ + i) * D_;
            size_t o = (size_t)soff + (size_t)(b * S_ + s) * D_;
            for (int d = tid; d < D_; d += 256) st_out(outv, o + d, ld_in(seq, r + d, isf), isf);
        } else {
            int t = blk - B_ * E_ - B_ * S_; int b = t / V_, v = t % V_;
            int i = vpos[b * V_ + v] + 1;
            size_t r = ((size_t)b * C_ + i) * D_;
            size_t o = (size_t)voff + (size_t)(b * V_ + v) * D_;
            for (int d = tid; d < D_; d += 256) st_out(outv, o + d, ld_in(seq, r + d, isf), isf);
        }
    } else if (blk < PREP_EATT) {
        int t = blk - PREP_GATHER;
        int b = t / (E_ * H_); int r = t % (E_ * H_); int e = r / H_; int h = r % H_;
        int i0 = epos[(b * E_ + e) * K_ + 0] + 1;
        int i1 = epos[(b * E_ + e) * K_ + 1] + 1;
        size_t a0 = (((size_t)b * H_ + h) * C_ + i0) * C_;
        size_t a1 = (((size_t)b * H_ + h) * C_ + i1) * C_;
        unsigned short* o = e_att + (((size_t)(b * E_ + e)) * H_ + h) * C_;
        for (int c = tid; c < C_; c += 256)
            o[c] = f2b(0.5f * (ld_in(att, a0 + c, isf) + ld_in(att, a1 + c, isf)));
    } else if (blk < PREP_TSEQ) {
        int t = blk - PREP_EATT;                 // b*192 + ct*12 + dt
        int b = t / 192; int r = t % 192; int ct = r / 12; int dt = r % 12;
        typedef unsigned short row65[65];
        row65* tile = (row65*)smem;
        for (int idx = tid; idx < 4096; idx += 256) {
            int cc = idx >> 6, dd = idx & 63;
            tile[cc][dd] = f2b(ld_in(seq, ((size_t)b * C_ + ct * 64 + cc) * D_ + dt * 64 + dd, isf));
        }
        __syncthreads();
        for (int idx = tid; idx < 4096; idx += 256) {
            int dd = idx >> 6, cc = idx & 63;
            seqT[((size_t)b * D_ + dt * 64 + dd) * C_ + ct * 64 + cc] = tile[cc][dd];
        }
    } else if (blk < PREP_TW) {
        int t = blk - PREP_TSEQ;                 // mat*336 + kt*12 + nt
        int mat = t / 336; int r = t % 336; int kt = r / 12; int nt = r % 12;
        const void* in = mat ? Wt_ : Wh;
        unsigned short* out = mat ? WtT : WtH;
        typedef unsigned short row65[65];
        row65* tile = (row65*)smem;
        for (int idx = tid; idx < 4096; idx += 256) {
            int kk = idx >> 6, nn = idx & 63;
            tile[kk][nn] = f2b(ld_in(in, ((size_t)kt * 64 + kk) * EMB_ + nt * 64 + nn, isf));
        }
        __syncthreads();
        for (int idx = tid; idx < 4096; idx += 256) {
            int nn = idx >> 6, kk = idx & 63;
            out[((size_t)nt * 64 + nn) * KHT_ + kt * 64 + kk] = tile[kk][nn];
        }
    } else {
        // t_bil: build W2 in MFMA-FRAGMENT ORDER so k_bil's inner-loop load is
        // one contiguous 1KB wave-load (R4 post-mortem: the old n-major layout
        // put the 16 l15 lanes at 96KB stride = 16 cache lines per load inst,
        // serializing the CU address unit).
        // W2[((g*8 + w)*64 + i)*1024 + jh*512 + q*128 + l15*8 + e]
        //   = Wb[kflat = g*4096 + i*64 + jh*32 + q*8 + e][n = w*16 + l15]
        int t = blk - PREP_TW;                   // 768 blocks: one (g, i) each
        int g = t >> 6, i = t & 63;
        unsigned short* raw = (unsigned short*)smem;   // [64 j][97 n]
        size_t src0 = ((size_t)g * 4096 + (size_t)i * 64) * NL_;
        for (int idx = tid; idx < 64 * NL_; idx += 256)
            raw[idx] = f2b(ld_in(Wb, src0 + idx, isf));
        __syncthreads();
        for (int idx = tid; idx < 8192; idx += 256) {
            int w = idx >> 10, o = idx & 1023;
            int jh = o >> 9, q = (o >> 7) & 3, l15 = (o >> 3) & 15, e = o & 7;
            int j = jh * 32 + q * 8 + e;
            int n = w * 16 + l15;
            unsigned short v = (n < NL_) ? raw[j * NL_ + n] : (unsigned short)0;
            WtB[(((size_t)(g * 8 + w) * 64 + i) << 10) + o] = v;
        }
    }
}

// ---------------------------------------------------------------------------
// K2 fused mid: [0,2048) htatt, [2048,4096) xbuild
__global__ __launch_bounds__(256) void k_mid(
    const unsigned short* __restrict__ e_att, const float* __restrict__ enth,
    const int* __restrict__ hts,
    unsigned short* __restrict__ htb,
    unsigned short* __restrict__ Xh, unsigned short* __restrict__ Xt)
{
    __shared__ float red[4];
    int blk = blockIdx.x, tid = threadIdx.x;
    if (blk < B_ * P_) {
        int b = blk >> 9;
        int he = hts[blk * 2 + 0], te = hts[blk * 2 + 1];
        const unsigned short* ph = e_att + (size_t)(b * E_ + he) * H_ * C_;
        const unsigned short* pt = e_att + (size_t)(b * E_ + te) * H_ * C_;
        float v[4]; float ls = 0.f;
        for (int ci = 0; ci < 4; ci++) {
            int c = tid + (ci << 8);
            float acc = 0.f;
#pragma unroll
            for (int h = 0; h < H_; h++) acc += b2f(ph[h * C_ + c]) * b2f(pt[h * C_ + c]);
            acc *= (1.0f / (float)H_);
            v[ci] = acc; ls += acc;
        }
        for (int off = 32; off > 0; off >>= 1) ls += __shfl_down(ls, off, 64);
        if ((tid & 63) == 0) red[tid >> 6] = ls;
        __syncthreads();
        float inv = 1.0f / (red[0] + red[1] + red[2] + red[3] + 1e-5f);
        for (int ci = 0; ci < 4; ci++)
            htb[((size_t)blk << 10) + tid + (ci << 8)] = f2b(v[ci] * inv);
    } else {
        int m = blk - B_ * P_; int b = m >> 9;
        int eh = hts[m * 2 + 0], et = hts[m * 2 + 1];
        const float* sh = enth + (size_t)(b * E_ + eh) * DNT_;
        const float* st = enth + (size_t)(b * E_ + et) * DNT_;
        for (int k = tid; k < DNT_; k += 256) {
            Xh[(size_t)m * KHT_ + k] = f2b(sh[k]);
            Xt[(size_t)m * KHT_ + k] = f2b(st[k]);
        }
    }
}

// ---------------------------------------------------------------------------
// bf16 MFMA GEMM, 64x64 tile, 4 waves 2x2, K-step 32, LDS staging (coalesced),
// register prefetch.
// zmode 0 (rs): z = batch; epilogue writes bf16 into Xh/Xt cols DNT_+n.
// zmode 1 (ht): z = mat (0=head,1=tail); epilogue bf16 tanh(acc+bias) -> oY.
__global__ __launch_bounds__(256) void k_gemm(
    const unsigned short* __restrict__ A0, const unsigned short* __restrict__ A1,
    const unsigned short* __restrict__ B0, const unsigned short* __restrict__ B1,
    long long lda, long long ldb, long long sAz, long long sBz,
    int nsteps, int zmode,
    const void* __restrict__ bias0, const void* __restrict__ bias1,
    unsigned short* __restrict__ oY0, unsigned short* __restrict__ oY1,
    unsigned short* __restrict__ oX1, unsigned short* __restrict__ oX2,
    const void* __restrict__ seq)
{
    int n0 = blockIdx.x * 64, m0 = blockIdx.y * 64, z = blockIdx.z;
    const unsigned short* Ab; const unsigned short* Bb;
    unsigned short* oY = nullptr; const void* bias = nullptr;
    if (zmode == 0) {
        Ab = A0 + (size_t)z * sAz; Bb = B0 + (size_t)z * sBz;
    } else {
        Ab = z ? A1 : A0; Bb = z ? B1 : B0;
        oY = z ? oY1 : oY0; bias = z ? bias1 : bias0;
    }
    __shared__ __align__(16) unsigned short a_lds[64][40];
    __shared__ __align__(16) unsigned short b_lds[64][40];
    int tid = threadIdx.x, lane = tid & 63, w = tid >> 6;
    int wm = (w >> 1) * 32, wn = (w & 1) * 32, q = lane >> 4, l15 = lane & 15;
    f32x4 acc00 = {0.f,0.f,0.f,0.f}, acc01 = acc00, acc10 = acc00, acc11 = acc00;
    int srow = tid >> 2, sch = (tid & 3) * 8;
    const unsigned short* pa = Ab + (size_t)(m0 + srow) * lda + sch;
    const unsigned short* pb = Bb + (size_t)(n0 + srow) * ldb + sch;
    int4 ra = *(const int4*)pa;
    int4 rb = *(const int4*)pb;
    for (int ks = 0; ks < nsteps; ks++) {
        __syncthreads();
        *(int4*)&a_lds[srow][sch] = ra;
        *(int4*)&b_lds[srow][sch] = rb;
        __syncthreads();
        if (ks + 1 < nsteps) {
            ra = *(const int4*)(pa + (size_t)(ks + 1) * 32);
            rb = *(const int4*)(pb + (size_t)(ks + 1) * 32);
        }
        bf16x8 a0 = *(const bf16x8*)&a_lds[wm + l15][q * 8];
        bf16x8 a1 = *(const bf16x8*)&a_lds[wm + 16 + l15][q * 8];
        bf16x8 b0 = *(const bf16x8*)&b_lds[wn + l15][q * 8];
        bf16x8 b1 = *(const bf16x8*)&b_lds[wn + 16 + l15][q * 8];
        acc00 = __builtin_amdgcn_mfma_f32_16x16x32_bf16(a0, b0, acc00, 0, 0, 0);
        acc01 = __builtin_amdgcn_mfma_f32_16x16x32_bf16(a0, b1, acc01, 0, 0, 0);
        acc10 = __builtin_amdgcn_mfma_f32_16x16x32_bf16(a1, b0, acc10, 0, 0, 0);
        acc11 = __builtin_amdgcn_mfma_f32_16x16x32_bf16(a1, b1, acc11, 0, 0, 0);
    }
    f32x4 accs[2][2] = {{acc00, acc01}, {acc10, acc11}};
    int isf = (zmode == 1) ? probe_isf(seq) : 0;
#pragma unroll
    for (int mt = 0; mt < 2; mt++)
#pragma unroll
        for (int nt = 0; nt < 2; nt++) {
            int gmb = m0 + wm + mt * 16 + q * 4;
            int gn  = n0 + wn + nt * 16 + l15;
            if (zmode == 0) {
#pragma unroll
                for (int r = 0; r < 4; r++) {
                    unsigned short v = f2b(accs[mt][nt][r]);
                    size_t o = (size_t)(z * P_ + gmb + r) * KHT_ + DNT_ + gn;
                    oX1[o] = v; oX2[o] = v;
                }
            } else {
                float bv = ld_in(bias, gn, isf);
#pragma unroll
                for (int r = 0; r < 4; r++)
                    oY[(size_t)(gmb + r) * EMB_ + gn] = f2b(tanhf(accs[mt][nt][r] + bv));
            }
        }
}

// ---------------------------------------------------------------------------
// Grouped bilinear v6: fragment-ordered W2 -> every inner-loop W load is one
// contiguous 1KB wave-load (chunk + lane*16B). Each wave streams a private
// 64KB slab of W2 sequentially (perfect coalescing, 1 line/load-quad,
// L2-resident: per-XCD working set 3 x 512KB). Compute/epilogue identical to
// v5 (partial-slab stores, no atomics) -> identical arithmetic & absmax.
__global__ __launch_bounds__(512) void k_bil(
    const unsigned short* __restrict__ hsB, const unsigned short* __restrict__ tsB,
    const unsigned short* __restrict__ W2, float* __restrict__ logitsP)
{
    // 768 blocks = 8 XCDs x 96; per XCD: 3 (g,ic) combos x 32 m-tiles
    int bid = blockIdx.x;
    int lin = (bid & 7) * 96 + (bid >> 3);
    int mt  = lin & 31;            // m-tile  [0,32)
    int gic = lin >> 5;            // [0,24)  (also the partial-slab index)
    int g   = gic >> 1;            // group   [0,12)
    int ic  = gic & 1;             // i-half  [0,2)
    int m0  = mt * 64;

    int tid = threadIdx.x, lane = tid & 63, w = tid >> 6;
    int q = lane >> 4, l15 = lane & 15;
    int ns = w * 16;               // wave-private n-subtile

    __shared__ __align__(16) unsigned short hsT[32][64];   // [i][m], 4 KB
    {
        int m = tid >> 3, i4 = (tid & 7) * 4;
        ushort4 hv = *(const ushort4*)&hsB[(size_t)(m0 + m) * EMB_ + g * 64 + ic * 32 + i4];
        hsT[i4 + 0][m] = hv.x; hsT[i4 + 1][m] = hv.y;
        hsT[i4 + 2][m] = hv.z; hsT[i4 + 3][m] = hv.w;
    }

    // ts A-fragments (invariant over i): 4 m-subtiles x 2 j-halves
    bf16x8 a[4][2];
#pragma unroll
    for (int ms = 0; ms < 4; ++ms)
#pragma unroll
        for (int jh = 0; jh < 2; ++jh)
            a[ms][jh] = *(const bf16x8*)&tsB[(size_t)(m0 + ms * 16 + l15) * EMB_
                                             + g * 64 + jh * 32 + q * 8];
    __syncthreads();

    // wave's W2 stream: chunk i is 1024 elems (2KB); wa at +lane*8, wb at +512
    const unsigned short* pw = W2 + (((size_t)(g * 8 + w) * 64 + ic * 32) << 10) + lane * 8;

    f32x4 acc[4];
#pragma unroll
    for (int ms = 0; ms < 4; ++ms) acc[ms] = (f32x4){0.f, 0.f, 0.f, 0.f};
    const f32x4 zf = {0.f, 0.f, 0.f, 0.f};

    // dist-2 software pipeline, static even/odd register slots
    bf16x8 w0a = *(const bf16x8*)(pw);
    bf16x8 w0b = *(const bf16x8*)(pw + 512);
    bf16x8 w1a = *(const bf16x8*)(pw + 1024);
    bf16x8 w1b = *(const bf16x8*)(pw + 1536);

#define BIL_STEP(ii, wa_, wb_)                                                             \
    do {                                                                                   \
        int ipre = (ii) + 2 <= 31 ? (ii) + 2 : 31;                                         \
        bf16x8 na = *(const bf16x8*)(pw + ((size_t)ipre << 10));                           \
        bf16x8 nb = *(const bf16x8*)(pw + ((size_t)ipre << 10) + 512);                     \
        f32x4 p[4];                                                                        \
        _Pragma("unroll")                                                                  \
        for (int ms = 0; ms < 4; ++ms) {                                                   \
            f32x4 t = __builtin_amdgcn_mfma_f32_16x16x32_bf16(a[ms][0], wa_, zf, 0, 0, 0); \
            p[ms]   = __builtin_amdgcn_mfma_f32_16x16x32_bf16(a[ms][1], wb_, t, 0, 0, 0);  \
        }                                                                                  \
        _Pragma("unroll")                                                                  \
        for (int ms = 0; ms < 4; ++ms) {                                                   \
            ushort4 hv = *(const ushort4*)&hsT[ii][ms * 16 + q * 4];                       \
            acc[ms][0] += b2f(hv.x) * p[ms][0];                                            \
            acc[ms][1] += b2f(hv.y) * p[ms][1];                                            \
            acc[ms][2] += b2f(hv.z) * p[ms][2];                                            \
            acc[ms][3] += b2f(hv.w) * p[ms][3];                                            \
        }                                                                                  \
        wa_ = na; wb_ = nb;                                                                \
    } while (0)

#pragma unroll 4
    for (int ii = 0; ii < 16; ++ii) {
        BIL_STEP(2 * ii,     w0a, w0b);
        BIL_STEP(2 * ii + 1, w1a, w1b);
    }
#undef BIL_STEP

    // conflict-free epilogue: each (mt,gic) block owns its [64][128] region
    float* outp = logitsP + ((size_t)gic * (B_ * P_) + m0) * NPAD_ + ns + l15;
#pragma unroll
    for (int ms = 0; ms < 4; ++ms)
#pragma unroll
        for (int r = 0; r < 4; ++r)
            outp[(size_t)(ms * 16 + q * 4 + r) * NPAD_] = acc[ms][r];
}

// ---------------------------------------------------------------------------
// final: reduce 24 bilinear partials + bias, n<97
__global__ __launch_bounds__(256) void k_fin(
    const float* __restrict__ logitsP, const void* __restrict__ b_bil,
    void* __restrict__ outv, const void* __restrict__ seq)
{
    int isf = probe_isf(seq);
    int idx = blockIdx.x * 256 + threadIdx.x;
    if (idx >= B_ * P_ * NL_) return;
    int m = idx / NL_, n = idx % NL_;
    float s = ld_in(b_bil, n, isf);
#pragma unroll
    for (int p = 0; p < NGIC_; ++p)
        s += logitsP[((size_t)p * (B_ * P_) + m) * NPAD_ + n];
    st_out(outv, idx, s, isf);
}

// ---------------------------------------------------------------------------
extern "C" void kernel_launch(void* const* d_in, const int* in_sizes, int n_in,
                              void* d_out, int out_size, void* d_ws, size_t ws_size,
                              hipStream_t stream)
{
    const void* seq    = d_in[0];
    const void* att    = d_in[1];
    const int*  epos   = (const int*)d_in[2];
    const int*  spos   = (const int*)d_in[3];
    const int*  vpos   = (const int*)d_in[4];
    const int*  hts    = (const int*)d_in[5];
    const void* ntype  = d_in[6];
    const void* W_head = d_in[7];
    const void* b_head = d_in[8];
    const void* W_tail = d_in[9];
    const void* b_tail = d_in[10];
    const void* W_bil  = d_in[11];
    const void* b_bil  = d_in[12];

    // output element offsets (dtype-agnostic)
    long long mention_off = (long long)B_ * P_ * NL_;
    long long sent_off    = mention_off + (long long)B_ * E_ * K_ * D_;
    long long virt_off    = sent_off + (long long)B_ * S_ * D_;

    // workspace carve (~75 MB)
    char* p = (char*)d_ws;
    auto alloc = [&](size_t bytes) { void* r = (void*)p; p += (bytes + 255) & ~(size_t)255; return r; };
    unsigned short* e_att   = (unsigned short*)alloc((size_t)B_ * E_ * H_ * C_ * 2);
    unsigned short* htb     = (unsigned short*)alloc((size_t)B_ * P_ * C_ * 2);
    unsigned short* seqT    = (unsigned short*)alloc((size_t)B_ * D_ * C_ * 2);
    unsigned short* WtH     = (unsigned short*)alloc((size_t)EMB_ * KHT_ * 2);
    unsigned short* WtT     = (unsigned short*)alloc((size_t)EMB_ * KHT_ * 2);
    unsigned short* WtB     = (unsigned short*)alloc((size_t)NPAD_ * KBIL_ * 2);  // W2, frag-order
    unsigned short* Xh      = (unsigned short*)alloc((size_t)B_ * P_ * KHT_ * 2);
    unsigned short* Xt      = (unsigned short*)alloc((size_t)B_ * P_ * KHT_ * 2);
    unsigned short* hsB     = (unsigned short*)alloc((size_t)B_ * P_ * EMB_ * 2);
    unsigned short* tsB     = (unsigned short*)alloc((size_t)B_ * P_ * EMB_ * 2);
    float*          logitsP = (float*)alloc((size_t)NGIC_ * B_ * P_ * NPAD_ * 4);  // 24 MB
    float*          enth    = (float*)alloc((size_t)B_ * E_ * DNT_ * 4);

    dim3 blk(256);
    k_prep<<<PREP_TBIL, blk, 0, stream>>>(
        seq, att, epos, spos, vpos, ntype, W_head, W_tail, W_bil,
        enth, e_att, seqT, WtH, WtT, WtB,
        d_out, mention_off, sent_off, virt_off);
    k_mid<<<2 * B_ * P_, blk, 0, stream>>>(e_att, enth, hts, htb, Xh, Xt);
    // rs GEMM: per batch [512 x 1024] @ [1024 x 768]^T -> X cols 1024..1791
    k_gemm<<<dim3(EMB_ / 64, P_ / 64, B_), blk, 0, stream>>>(
        htb, nullptr, seqT, nullptr, C_, C_,
        (long long)P_ * C_, (long long)D_ * C_, C_ / 32, 0,
        nullptr, nullptr, nullptr, nullptr, Xh, Xt, seq);
    // fused head+tail: [2048 x 1792] @ [1792 x 768]^T, tanh+bias -> bf16 hsB/tsB
    k_gemm<<<dim3(EMB_ / 64, (B_ * P_) / 64, 2), blk, 0, stream>>>(
        Xh, Xt, WtH, WtT, KHT_, KHT_, 0, 0, KHT_ / 32, 1,
        b_head, b_tail, hsB, tsB, nullptr, nullptr, seq);
    // bilinear v6: 768 blocks (32 m-tiles x 12 g x 2 i-halves), XCD-affine,
    // fragment-ordered streaming W loads, partial-slab epilogue
    k_bil<<<dim3(768), dim3(512), 0, stream>>>(hsB, tsB, WtB, logitsP);
    k_fin<<<(B_ * P_ * NL_ + 255) / 256, blk, 0, stream>>>(logitsP, b_bil, d_out, seq);
}